// Round 11
// baseline (1290.118 us; speedup 1.0000x reference)
//
#include <hip/hip_runtime.h>
#include <math.h>

#define TPB 256
#define C0F 20.0f

typedef __attribute__((ext_vector_type(4))) float f32x4;
typedef short s16x8 __attribute__((ext_vector_type(8)));

static inline int cdiv(int a, int b) { return (a + b - 1) / b; }

#define GLOAD_LDS16(g, l)                                                        \
  __builtin_amdgcn_global_load_lds(                                              \
      (const __attribute__((address_space(1))) unsigned int*)(const void*)(g),   \
      (__attribute__((address_space(3))) unsigned int*)(void*)(l), 16, 0, 0)

__device__ __forceinline__ unsigned short f2bf_rne(float f) {
  unsigned int u = __float_as_uint(f);
  return (unsigned short)((u + 0x7FFFu + ((u >> 16) & 1u)) >> 16);
}
__device__ __forceinline__ float bf2f(unsigned short h) {
  return __uint_as_float(((unsigned int)h) << 16);
}

// ---------------- 3-term split-bf16 pack, A and B in one launch -------------
__global__ __launch_bounds__(TPB) void pack_split2(const float* __restrict__ XA,
                                                   const float* __restrict__ XB,
                                                   unsigned short* __restrict__ outA,
                                                   unsigned short* __restrict__ outB,
                                                   int M, int D, int K2p,
                                                   int codesA, int codesB) {
  int id = blockIdx.x * TPB + threadIdx.x;
  if (id >= M * K2p) return;
  const float* X = blockIdx.y ? XB : XA;
  unsigned short* out = blockIdx.y ? outB : outA;
  int codes = blockIdx.y ? codesB : codesA;
  int m = id / K2p, k = id - m * K2p;
  int s = k / D;
  unsigned short v = 0;
  if (s < 6) {
    int d = k - s * D;
    float a = X[(size_t)m * D + d];
    unsigned short h = f2bf_rne(a);
    int code = (codes >> (2 * s)) & 3;
    if (code == 0) {
      v = h;
    } else {
      float r1 = a - bf2f(h);
      unsigned short mi = f2bf_rne(r1);
      if (code == 1) v = mi;
      else v = f2bf_rne(r1 - bf2f(mi));
    }
  }
  out[id] = v;
}

// ---------------- small-GEMM (128x128, 4 waves) + fused exp-sum partials ----
template <bool EXACT, bool ROWSTATS>
__global__ __launch_bounds__(TPB) void gemm_bf16_nt(const unsigned short* __restrict__ A,
                                                    const unsigned short* __restrict__ B,
                                                    float* __restrict__ C,
                                                    int M, int N, int K, int gx, int gy,
                                                    float* __restrict__ cps,
                                                    float* __restrict__ rps) {
  __shared__ __align__(16) unsigned short As[128 * 64];
  __shared__ __align__(16) unsigned short Bs[128 * 64];
  const int tid = threadIdx.x;
  const int lane = tid & 63;
  const int w = tid >> 6;
  const int wm = w >> 1, wn = w & 1;

  const int nwg = gridDim.x;
  const int q = nwg >> 3, r = nwg & 7;
  const int xcd = blockIdx.x & 7, pos = blockIdx.x >> 3;
  const int wgid = (xcd < r ? xcd * (q + 1) : r * (q + 1) + (xcd - r) * q) + pos;
  const int tpg = 8 * gx;
  const int g = wgid / tpg;
  const int rem = wgid - g * tpg;
  const int rows = min(8, gy - g * 8);
  const int bx = rem / rows;
  const int by = g * 8 + rem - bx * rows;
  const int bm = by * 128, bn = bx * 128;

  f32x4 acc[4][4];
#pragma unroll
  for (int m = 0; m < 4; ++m)
#pragma unroll
    for (int n = 0; n < 4; ++n) acc[m][n] = (f32x4){0.f, 0.f, 0.f, 0.f};

  const unsigned short* gA[4];
  const unsigned short* gB[4];
#pragma unroll
  for (int i = 0; i < 4; ++i) {
    int qq = (w * 4 + i) * 64 + lane;
    int rr = qq >> 3;
    int cc = (qq & 7) ^ (rr & 7);
    int ga = bm + rr, gb = bn + rr;
    if (!EXACT) { if (ga >= M) ga = M - 1; if (gb >= N) gb = N - 1; }
    gA[i] = A + (size_t)ga * K + cc * 8;
    gB[i] = B + (size_t)gb * K + cc * 8;
  }

  for (int k0 = 0; k0 < K; k0 += 64) {
#pragma unroll
    for (int i = 0; i < 4; ++i) {
      GLOAD_LDS16(gA[i] + k0, As + (w * 4 + i) * 512);
      GLOAD_LDS16(gB[i] + k0, Bs + (w * 4 + i) * 512);
    }
    __syncthreads();
#pragma unroll
    for (int ks = 0; ks < 2; ++ks) {
      s16x8 af[4], bfr[4];
      const int c0 = ks * 4 + (lane >> 4);
#pragma unroll
      for (int m = 0; m < 4; ++m) {
        int ra = wm * 64 + m * 16 + (lane & 15);
        af[m] = *(const s16x8*)(As + ra * 64 + ((c0 ^ (ra & 7)) * 8));
        int rb = wn * 64 + m * 16 + (lane & 15);
        bfr[m] = *(const s16x8*)(Bs + rb * 64 + ((c0 ^ (rb & 7)) * 8));
      }
#pragma unroll
      for (int m = 0; m < 4; ++m)
#pragma unroll
        for (int n = 0; n < 4; ++n)
          acc[m][n] = __builtin_amdgcn_mfma_f32_16x16x32_bf16(af[m], bfr[n], acc[m][n], 0, 0, 0);
    }
    __syncthreads();
  }

#pragma unroll
  for (int m = 0; m < 4; ++m) {
    int row0 = bm + wm * 64 + m * 16 + (lane >> 4) * 4;
#pragma unroll
    for (int n = 0; n < 4; ++n) {
      int col = bn + wn * 64 + n * 16 + (lane & 15);
      if (EXACT || col < N) {
#pragma unroll
        for (int j = 0; j < 4; ++j) {
          int r2 = row0 + j;
          if (EXACT || r2 < M) C[(size_t)r2 * N + col] = acc[m][n][j];
        }
      }
    }
  }

#pragma unroll
  for (int m = 0; m < 4; ++m)
#pragma unroll
    for (int n = 0; n < 4; ++n)
#pragma unroll
      for (int j = 0; j < 4; ++j) acc[m][n][j] = __expf(acc[m][n][j] - C0F);

  float* scs = (float*)As;  // [8][128]
  const int slot = wm * 4 + (lane >> 4);
#pragma unroll
  for (int n = 0; n < 4; ++n) {
    int lcol = wn * 64 + n * 16 + (lane & 15);
    float s = 0.f;
#pragma unroll
    for (int m = 0; m < 4; ++m)
#pragma unroll
      for (int j = 0; j < 4; ++j) {
        if (!EXACT) {
          int grow = bm + wm * 64 + m * 16 + (lane >> 4) * 4 + j;
          if (grow >= M) continue;
        }
        s += acc[m][n][j];
      }
    scs[slot * 128 + lcol] = s;
  }
  __syncthreads();
  if (tid < 128) {
    float s = 0.f;
#pragma unroll
    for (int k = 0; k < 8; ++k) s += scs[k * 128 + tid];
    if (EXACT || bn + tid < N) cps[(size_t)by * N + bn + tid] = s;
  }

  if (ROWSTATS) {
    float* srs = (float*)Bs;  // [2][128]
#pragma unroll
    for (int m = 0; m < 4; ++m)
#pragma unroll
      for (int j = 0; j < 4; ++j) {
        float s = 0.f;
#pragma unroll
        for (int n = 0; n < 4; ++n) {
          if (!EXACT) {
            int gcol = bn + wn * 64 + n * 16 + (lane & 15);
            if (gcol >= N) continue;
          }
          s += acc[m][n][j];
        }
#pragma unroll
        for (int d = 1; d < 16; d <<= 1) s += __shfl_xor(s, d);
        if ((lane & 15) == 0) srs[wn * 128 + wm * 64 + m * 16 + (lane >> 4) * 4 + j] = s;
      }
    __syncthreads();
    if (tid < 128) {
      float s = srs[tid] + srs[128 + tid];
      if (EXACT || bm + tid < M) rps[(size_t)bx * M + bm + tid] = s;
    }
  }
}

// ---------------- big-GEMM (128x256, 8 waves, EXACT, BK=64 single-buffer) ----
// R7-proven (121 us, MfmaUtil 36%). R8: no min-occupancy (spills acc).
// R9: no BK=32 dbuf (doubles barrier drains, 2x regression).
template <bool ROWSTATS>
__global__ __launch_bounds__(512) void gemm_big(const unsigned short* __restrict__ A,
                                                const unsigned short* __restrict__ B,
                                                float* __restrict__ C,
                                                int M, int N, int K, int gx, int gy,
                                                float* __restrict__ cps,
                                                float* __restrict__ rps) {
  __shared__ __align__(16) unsigned short As[128 * 64];   // 16 KB
  __shared__ __align__(16) unsigned short Bs[256 * 64];   // 32 KB
  const int tid = threadIdx.x;
  const int lane = tid & 63;
  const int w = tid >> 6;          // 0..7
  const int wm = w >> 2, wn = w & 3;

  const int nwg = gridDim.x;
  const int q = nwg >> 3, r = nwg & 7;
  const int xcd = blockIdx.x & 7, pos = blockIdx.x >> 3;
  const int wgid = (xcd < r ? xcd * (q + 1) : r * (q + 1) + (xcd - r) * q) + pos;
  const int tpg = 8 * gx;
  const int g = wgid / tpg;
  const int rem = wgid - g * tpg;
  const int rows = min(8, gy - g * 8);
  const int bx = rem / rows;
  const int by = g * 8 + rem - bx * rows;
  const int bm = by * 128, bn = bx * 256;

  f32x4 acc[4][4];
#pragma unroll
  for (int m = 0; m < 4; ++m)
#pragma unroll
    for (int n = 0; n < 4; ++n) acc[m][n] = (f32x4){0.f, 0.f, 0.f, 0.f};

  const unsigned short* gA[2];
  const unsigned short* gB[4];
#pragma unroll
  for (int i = 0; i < 2; ++i) {
    int qq = i * 512 + tid;
    int rr = qq >> 3;
    int cc = (qq & 7) ^ (rr & 7);
    gA[i] = A + (size_t)(bm + rr) * K + cc * 8;
  }
#pragma unroll
  for (int i = 0; i < 4; ++i) {
    int qq = i * 512 + tid;
    int rr = qq >> 3;
    int cc = (qq & 7) ^ (rr & 7);
    gB[i] = B + (size_t)(bn + rr) * K + cc * 8;
  }

  for (int k0 = 0; k0 < K; k0 += 64) {
#pragma unroll
    for (int i = 0; i < 2; ++i)
      GLOAD_LDS16(gA[i] + k0, As + (i * 8 + w) * 512);
#pragma unroll
    for (int i = 0; i < 4; ++i)
      GLOAD_LDS16(gB[i] + k0, Bs + (i * 8 + w) * 512);
    __syncthreads();
#pragma unroll
    for (int ks = 0; ks < 2; ++ks) {
      s16x8 af[4], bfr[4];
      const int c0 = ks * 4 + (lane >> 4);
#pragma unroll
      for (int m = 0; m < 4; ++m) {
        int ra = wm * 64 + m * 16 + (lane & 15);
        af[m] = *(const s16x8*)(As + ra * 64 + ((c0 ^ (ra & 7)) * 8));
        int rb = wn * 64 + m * 16 + (lane & 15);
        bfr[m] = *(const s16x8*)(Bs + rb * 64 + ((c0 ^ (rb & 7)) * 8));
      }
#pragma unroll
      for (int m = 0; m < 4; ++m)
#pragma unroll
        for (int n = 0; n < 4; ++n)
          acc[m][n] = __builtin_amdgcn_mfma_f32_16x16x32_bf16(af[m], bfr[n], acc[m][n], 0, 0, 0);
    }
    __syncthreads();
  }

#pragma unroll
  for (int m = 0; m < 4; ++m) {
    int row0 = bm + wm * 64 + m * 16 + (lane >> 4) * 4;
#pragma unroll
    for (int n = 0; n < 4; ++n) {
      int col = bn + wn * 64 + n * 16 + (lane & 15);
#pragma unroll
      for (int j = 0; j < 4; ++j)
        C[(size_t)(row0 + j) * N + col] = acc[m][n][j];
    }
  }

#pragma unroll
  for (int m = 0; m < 4; ++m)
#pragma unroll
    for (int n = 0; n < 4; ++n)
#pragma unroll
      for (int j = 0; j < 4; ++j) acc[m][n][j] = __expf(acc[m][n][j] - C0F);

  float* scs = (float*)As;  // [8][256]
  const int slot = wm * 4 + (lane >> 4);
#pragma unroll
  for (int n = 0; n < 4; ++n) {
    int lcol = wn * 64 + n * 16 + (lane & 15);
    float s = 0.f;
#pragma unroll
    for (int m = 0; m < 4; ++m)
#pragma unroll
      for (int j = 0; j < 4; ++j) s += acc[m][n][j];
    scs[slot * 256 + lcol] = s;
  }
  __syncthreads();
  if (tid < 256) {
    float s = 0.f;
#pragma unroll
    for (int k = 0; k < 8; ++k) s += scs[k * 256 + tid];
    cps[(size_t)by * N + bn + tid] = s;
  }

  if (ROWSTATS) {
    float* srs = (float*)Bs;  // [4][128]
#pragma unroll
    for (int m = 0; m < 4; ++m)
#pragma unroll
      for (int j = 0; j < 4; ++j) {
        float s = 0.f;
#pragma unroll
        for (int n = 0; n < 4; ++n) s += acc[m][n][j];
#pragma unroll
        for (int d = 1; d < 16; d <<= 1) s += __shfl_xor(s, d);
        if ((lane & 15) == 0) srs[wn * 128 + wm * 64 + m * 16 + (lane >> 4) * 4 + j] = s;
      }
    __syncthreads();
    if (tid < 128) {
      float s = (srs[tid] + srs[128 + tid]) + (srs[256 + tid] + srs[384 + tid]);
      rps[(size_t)bx * M + bm + tid] = s;
    }
  }
}

// ---------------- combine: out[s] = ln(sum of chunk partials) ----------------
__global__ __launch_bounds__(TPB) void logsum_combine2(const float* __restrict__ cps,
                                                       const float* __restrict__ rps,
                                                       int S, int nch_c, int nch_r,
                                                       float* __restrict__ out_c,
                                                       float* __restrict__ out_r) {
  int s = blockIdx.x * TPB + threadIdx.x;
  if (s >= S) return;
  const float* ps = blockIdx.y ? rps : cps;
  int nch = blockIdx.y ? nch_r : nch_c;
  float a = 0.f;
  for (int c = 0; c < nch; ++c) a += ps[(size_t)c * S + s];
  (blockIdx.y ? out_r : out_c)[s] = logf(a);
}

// ---------------- finalize variants ----------------
__global__ __launch_bounds__(TPB) void finalize_argmax(const float* __restrict__ sim, int S,
                                                       const float* __restrict__ pen,
                                                       int* __restrict__ amax) {
  __shared__ float rv[TPB];
  __shared__ int ri[TPB];
  const int l = blockIdx.x;
  const f32x4* row = (const f32x4*)(sim + (size_t)l * S);
  const f32x4* pv = (const f32x4*)pen;
  float bv = -INFINITY;
  int bi = 0;
  for (int j4 = threadIdx.x; j4 < (S >> 2); j4 += TPB) {
    f32x4 v = row[j4];
    f32x4 p = pv[j4];
#pragma unroll
    for (int k = 0; k < 4; ++k) {
      float sc = 2.f * v[k] - p[k];
      if (sc > bv) { bv = sc; bi = j4 * 4 + k; }
    }
  }
  rv[threadIdx.x] = bv;
  ri[threadIdx.x] = bi;
  __syncthreads();
  for (int stp = TPB / 2; stp > 0; stp >>= 1) {
    if (threadIdx.x < stp) {
      float v2 = rv[threadIdx.x + stp];
      int i2 = ri[threadIdx.x + stp];
      if (v2 > rv[threadIdx.x] || (v2 == rv[threadIdx.x] && i2 < ri[threadIdx.x])) {
        rv[threadIdx.x] = v2;
        ri[threadIdx.x] = i2;
      }
    }
    __syncthreads();
  }
  if (threadIdx.x == 0) amax[l] = ri[0];
}

__global__ __launch_bounds__(TPB) void finalize_write(float* __restrict__ sim, int S,
                                                      const float* __restrict__ cls,
                                                      const float* __restrict__ rls,
                                                      int* __restrict__ amax) {
  __shared__ float rv[TPB];
  __shared__ int ri[TPB];
  const int l = blockIdx.x;
  const float rl = rls[l] + 2.0f * C0F;
  f32x4* row = (f32x4*)(sim + (size_t)l * S);
  const f32x4* cv = (const f32x4*)cls;
  float bv = -INFINITY;
  int bi = 0;
  for (int j4 = threadIdx.x; j4 < (S >> 2); j4 += TPB) {
    f32x4 v = row[j4];
    f32x4 cl = cv[j4];
    f32x4 o;
#pragma unroll
    for (int k = 0; k < 4; ++k) {
      float conf = expf(2.f * v[k] - cl[k] - rl);
      o[k] = conf;
      if (conf > bv) { bv = conf; bi = j4 * 4 + k; }
    }
    row[j4] = o;
  }
  rv[threadIdx.x] = bv;
  ri[threadIdx.x] = bi;
  __syncthreads();
  for (int stp = TPB / 2; stp > 0; stp >>= 1) {
    if (threadIdx.x < stp) {
      float v2 = rv[threadIdx.x + stp];
      int i2 = ri[threadIdx.x + stp];
      if (v2 > rv[threadIdx.x] || (v2 == rv[threadIdx.x] && i2 < ri[threadIdx.x])) {
        rv[threadIdx.x] = v2;
        ri[threadIdx.x] = i2;
      }
    }
    __syncthreads();
  }
  if (threadIdx.x == 0) amax[l] = ri[0];
}

__global__ __launch_bounds__(TPB) void finalize_mask(float* __restrict__ sim, int S,
                                                     const float* __restrict__ cls,
                                                     const float* __restrict__ rls) {
  const int l = blockIdx.x;
  const float rl = rls[l] + 2.0f * C0F - 2.302585093f;  // -ln(10)
  f32x4* row = (f32x4*)(sim + (size_t)l * S);
  const f32x4* cv = (const f32x4*)cls;
  for (int j4 = threadIdx.x; j4 < (S >> 2); j4 += TPB) {
    f32x4 v = row[j4];
    f32x4 cl = cv[j4];
    f32x4 o;
#pragma unroll
    for (int k = 0; k < 4; ++k) {
      float c = expf(2.f * v[k] - cl[k] - rl);
      o[k] = (c > 1.0f) ? c : 0.0f;
    }
    row[j4] = o;
  }
}

// ---------------- fused gather-convs (builders folded in) ----------------
// conv16: Y(256 x 400) = W16(256x768) . X, X[c][p] = c<256? t2[p,c] :
//         c<512? f116_0[p,c-256] : f116_1[idx[p], c-512]
__global__ __launch_bounds__(TPB) void conv16_f(const float* __restrict__ W,
                                                const float* __restrict__ t2,
                                                const float* __restrict__ f0,
                                                const float* __restrict__ f1,
                                                const int* __restrict__ idx,
                                                float* __restrict__ Y) {
  __shared__ float red[TPB];
  const int o = blockIdx.y;
  const int pl = threadIdx.x & 63;
  const int p = blockIdx.x * 64 + pl;
  const int cg = threadIdx.x >> 6;
  const float* wr = W + (size_t)o * 768;
  float a = 0.f;
  if (p < 400) {
    int ip = idx[p];
    const float* r0 = t2 + p * 256;
    const float* r1 = f0 + p * 256;
    const float* r2 = f1 + ip * 256;
    for (int c = cg; c < 256; c += 4) {
      a += wr[c] * r0[c];
      a += wr[c + 256] * r1[c];
      a += wr[c + 512] * r2[c];
    }
  }
  red[threadIdx.x] = a;
  __syncthreads();
  if (threadIdx.x < 64) {
    float s = (red[threadIdx.x] + red[threadIdx.x + 64]) +
              (red[threadIdx.x + 128] + red[threadIdx.x + 192]);
    if (p < 400) Y[(size_t)o * 400 + p] = s;
  }
}

// conv8: Y(256 x 1600) = W8(256x512) . X, X[c][p] = c<256? f18_0[p,c] : f18_1[idx[p],c-256]
__global__ __launch_bounds__(TPB) void conv8_f(const float* __restrict__ W,
                                               const float* __restrict__ f0,
                                               const float* __restrict__ f1,
                                               const int* __restrict__ idx,
                                               float* __restrict__ Y) {
  __shared__ float red[TPB];
  const int o = blockIdx.y;
  const int pl = threadIdx.x & 63;
  const int p = blockIdx.x * 64 + pl;
  const int cg = threadIdx.x >> 6;
  const float* wr = W + (size_t)o * 512;
  float a = 0.f;
  if (p < 1600) {
    int ip = idx[p];
    const float* r0 = f0 + p * 256;
    const float* r1 = f1 + ip * 256;
    for (int c = cg; c < 256; c += 4) {
      a += wr[c] * r0[c];
      a += wr[c + 256] * r1[c];
    }
  }
  red[threadIdx.x] = a;
  __syncthreads();
  if (threadIdx.x < 64) {
    float s = (red[threadIdx.x] + red[threadIdx.x + 64]) +
              (red[threadIdx.x + 128] + red[threadIdx.x + 192]);
    if (p < 1600) Y[(size_t)o * 1600 + p] = s;
  }
}

// convt3: Y(128 x 100) = Wt3(128x1100) . X, X rows: [t3(196, [p][c]); t2p(256,[c][p]);
//         f18p(256,[c][p]); f14p(392,[c][p])]
__global__ __launch_bounds__(TPB) void convt3_f(const float* __restrict__ W,
                                                const float* __restrict__ t3,
                                                const float* __restrict__ t2p,
                                                const float* __restrict__ f18p,
                                                const float* __restrict__ f14p,
                                                float* __restrict__ Y) {
  __shared__ float red[TPB];
  const int o = blockIdx.y;
  const int pl = threadIdx.x & 63;
  const int p = blockIdx.x * 64 + pl;
  const int cg = threadIdx.x >> 6;
  const float* wr = W + (size_t)o * 1100;
  float a = 0.f;
  if (p < 100) {
    const float* r0 = t3 + p * 196;
    for (int c = cg; c < 196; c += 4) a += wr[c] * r0[c];
    for (int c = cg; c < 256; c += 4) {
      a += wr[196 + c] * t2p[c * 100 + p];
      a += wr[452 + c] * f18p[c * 100 + p];
    }
    for (int c = cg; c < 392; c += 4) a += wr[708 + c] * f14p[c * 100 + p];
  }
  red[threadIdx.x] = a;
  __syncthreads();
  if (threadIdx.x < 64) {
    float s = (red[threadIdx.x] + red[threadIdx.x + 64]) +
              (red[threadIdx.x + 128] + red[threadIdx.x + 192]);
    if (p < 100) Y[(size_t)o * 100 + p] = s;
  }
}

// convt4: Y(128 x 25) = Wt4(128x256) . X, X[c][p] = c<128? t3d[c,p] : t4[p, c-128]
__global__ __launch_bounds__(TPB) void convt4_f(const float* __restrict__ W,
                                                const float* __restrict__ t3d,
                                                const float* __restrict__ t4,
                                                float* __restrict__ Y) {
  __shared__ float red[TPB];
  const int o = blockIdx.y;
  const int pl = threadIdx.x & 63;
  const int p = blockIdx.x * 64 + pl;
  const int cg = threadIdx.x >> 6;
  const float* wr = W + (size_t)o * 256;
  float a = 0.f;
  if (p < 25) {
    const float* r1 = t4 + p * 128;
    for (int c = cg; c < 128; c += 4) {
      a += wr[c] * t3d[c * 25 + p];
      a += wr[128 + c] * r1[c];
    }
  }
  red[threadIdx.x] = a;
  __syncthreads();
  if (threadIdx.x < 64) {
    float s = (red[threadIdx.x] + red[threadIdx.x + 64]) +
              (red[threadIdx.x + 128] + red[threadIdx.x + 192]);
    if (p < 25) Y[(size_t)o * 25 + p] = s;
  }
}

// ---------------- pools ----------------
__global__ void pool_k(const float* __restrict__ in, float* __restrict__ out, int C, int H, int f) {
  int h = H / f;
  int id = blockIdx.x * TPB + threadIdx.x;
  if (id >= C * h * h) return;
  int c = id / (h * h);
  int r = id % (h * h);
  int py = r / h, px = r % h;
  float s = 0.f;
  for (int i = 0; i < f; ++i)
    for (int j = 0; j < f; ++j)
      s += in[(size_t)c * H * H + (size_t)(py * f + i) * H + (px * f + j)];
  out[id] = s / (float)(f * f);
}

// pool pair: y==0: conv18b (256,40,f4) -> f18p ; y==1: t2_ (256,20,f2) -> t2p
__global__ void pool_pair(const float* __restrict__ in0, const float* __restrict__ in1,
                          float* __restrict__ out0, float* __restrict__ out1) {
  int id = blockIdx.x * TPB + threadIdx.x;
  if (id >= 256 * 100) return;
  int c = id / 100;
  int r = id % 100;
  int py = r / 10, px = r % 10;
  if (blockIdx.y == 0) {
    float s = 0.f;
    for (int i = 0; i < 4; ++i)
      for (int j = 0; j < 4; ++j)
        s += in0[(size_t)c * 1600 + (size_t)(py * 4 + i) * 40 + (px * 4 + j)];
    out0[id] = s * 0.0625f;
  } else {
    float s = 0.f;
    for (int i = 0; i < 2; ++i)
      for (int j = 0; j < 2; ++j)
        s += in1[(size_t)c * 400 + (size_t)(py * 2 + i) * 20 + (px * 2 + j)];
    out1[id] = s * 0.25f;
  }
}

__global__ void pool14(const float* __restrict__ f0, const float* __restrict__ f1,
                       const int* __restrict__ idx, float* __restrict__ out) {
  int id = blockIdx.x * TPB + threadIdx.x;
  if (id >= 392 * 100) return;
  int c = id / 100;
  int r = id % 100;
  int py = r / 10, px = r % 10;
  float s = 0.f;
  for (int i = 0; i < 8; ++i)
    for (int j = 0; j < 8; ++j) {
      int p = (py * 8 + i) * 80 + (px * 8 + j);
      float v = (c < 196) ? f0[p * 196 + c] : f1[idx[p] * 196 + (c - 196)];
      s += v;
    }
  out[id] = s * (1.0f / 64.0f);
}

// ---------------- topic: 4 d-groups per row, 200 blocks ----------------
__global__ __launch_bounds__(TPB) void topic_k4(const float* __restrict__ f0,
                                                const float* __restrict__ f1,
                                                const float* __restrict__ t4d,
                                                float* __restrict__ out) {
  __shared__ float s_t4[25 * 128];     // 12.8 KB
  __shared__ float red[4 * 64 * 25];   // 25.6 KB
  for (int i = threadIdx.x; i < 25 * 128; i += TPB) {
    int k = i >> 7, d = i & 127;
    s_t4[i] = t4d[d * 25 + k];   // t4seq[k][d]
  }
  __syncthreads();
  const int r = threadIdx.x & 63;
  const int gq = threadIdx.x >> 6;
  const int m = blockIdx.x * 64 + r;
  const f32x4* row = (const f32x4*)((m < 6400) ? (f0 + (size_t)m * 128)
                                               : (f1 + (size_t)(m - 6400) * 128));
  float acc[25];
#pragma unroll
  for (int k = 0; k < 25; ++k) acc[k] = 0.f;
  for (int d4 = 0; d4 < 8; ++d4) {
    f32x4 x = row[gq * 8 + d4];
#pragma unroll
    for (int k = 0; k < 25; ++k) {
      const float* t = s_t4 + k * 128 + (gq * 8 + d4) * 4;
      acc[k] += x[0] * t[0] + x[1] * t[1] + x[2] * t[2] + x[3] * t[3];
    }
  }
#pragma unroll
  for (int k = 0; k < 25; ++k) red[(gq * 64 + r) * 25 + k] = acc[k];
  __syncthreads();
  if (gq == 0) {
    int best = 0;
    float bv = -INFINITY;
#pragma unroll
    for (int k = 0; k < 25; ++k) {
      float s = (red[r * 25 + k] + red[(64 + r) * 25 + k]) +
                (red[(128 + r) * 25 + k] + red[(192 + r) * 25 + k]);
      if (s > bv) { bv = s; best = k; }
    }
    out[m] = (float)best;
  }
}

extern "C" void kernel_launch(void* const* d_in, const int* in_sizes, int n_in,
                              void* d_out, int out_size, void* d_ws, size_t ws_size,
                              hipStream_t stream) {
  const float* f12_0 = (const float*)d_in[0];
  const float* f12_1 = (const float*)d_in[1];
  const float* f14_0 = (const float*)d_in[2];
  const float* f14_1 = (const float*)d_in[3];
  const float* f18_0 = (const float*)d_in[4];
  const float* f18_1 = (const float*)d_in[5];
  const float* f116_0 = (const float*)d_in[6];
  const float* f116_1 = (const float*)d_in[7];
  const float* t2 = (const float*)d_in[9];
  const float* t3 = (const float*)d_in[10];
  const float* t4 = (const float*)d_in[11];
  const float* W16 = (const float*)d_in[12];
  const float* W8 = (const float*)d_in[13];
  const float* Wt3 = (const float*)d_in[14];
  const float* Wt4 = (const float*)d_in[15];

  float* out = (float*)d_out;
  float* conf18 = out;
  float* conf12 = out + 2560000;
  float* topic = out + 2560000 + 40960000;

  float* w = (float*)d_ws;
  auto alloc = [&](size_t n) { float* p = w; w += ((n + 63) & ~(size_t)63); return p; };

  unsigned short* pA = (unsigned short*)alloc(6400 * 1216 / 2);
  unsigned short* pB = (unsigned short*)alloc(6400 * 1216 / 2);
  float* sim116 = alloc(400 * 400);
  float* pen116 = alloc(400);
  int* idx116 = (int*)alloc(400);
  float* cls18 = alloc(1600); float* rls18 = alloc(1600);
  int* idx18 = (int*)alloc(1600);
  float* pen14 = alloc(6400);
  int* idx14 = (int*)alloc(6400);
  float* cls12 = alloc(6400); float* rls12 = alloc(6400);
  float* cps = alloc(50 * 6400);
  float* rps = alloc(50 * 6400);
  float* t2_ = alloc(256 * 400);
  float* conv18b = alloc(256 * 1600);
  float* f18p = alloc(256 * 100);
  float* t2p = alloc(256 * 100);
  float* f14p = alloc(392 * 100);
  float* t3conv = alloc(128 * 100);
  float* t3d = alloc(128 * 25);
  float* t4d = alloc(128 * 25);

  // 6-section codes: A: [h,h,m,h,l,m]  B: [h,m,h,l,h,m]  ->  hh+hm+mh+hl+lh+mm
  const int CA = 0 | (0 << 2) | (1 << 4) | (0 << 6) | (2 << 8) | (1 << 10);
  const int CB = 0 | (1 << 2) | (0 << 4) | (2 << 6) | (0 << 8) | (1 << 10);

  // ---------------- conf116 -> idx116 (D=256, K2=1536) ----------------
  {
    int L = 400, S = 400, K2 = 1536;
    int gx = cdiv(S, 128), gy = cdiv(L, 128);
    pack_split2<<<dim3(cdiv(L * K2, TPB), 2), TPB, 0, stream>>>(f116_0, f116_1, pA, pB, L, 256, K2, CA, CB);
    gemm_bf16_nt<false, false><<<gx * gy, TPB, 0, stream>>>(pA, pB, sim116, L, S, K2, gx, gy,
                                                            cps, nullptr);
    logsum_combine2<<<dim3(cdiv(S, TPB), 1), TPB, 0, stream>>>(cps, nullptr, S, gy, 0, pen116, nullptr);
    finalize_argmax<<<L, TPB, 0, stream>>>(sim116, S, pen116, idx116);
  }

  conv16_f<<<dim3(cdiv(400, 64), 256), TPB, 0, stream>>>(W16, t2, f116_0, f116_1, idx116, t2_);

  // ---------------- conf18 (output) + idx18 (D=256, K2=1536) ----------------
  {
    int L = 1600, S = 1600, K2 = 1536;
    int gx = cdiv(S, 128), gy = cdiv(L, 128);
    pack_split2<<<dim3(cdiv(L * K2, TPB), 2), TPB, 0, stream>>>(f18_0, f18_1, pA, pB, L, 256, K2, CA, CB);
    gemm_bf16_nt<false, true><<<gx * gy, TPB, 0, stream>>>(pA, pB, conf18, L, S, K2, gx, gy,
                                                           cps, rps);
    logsum_combine2<<<dim3(cdiv(S, TPB), 2), TPB, 0, stream>>>(cps, rps, S, gy, gx, cls18, rls18);
    finalize_write<<<L, TPB, 0, stream>>>(conf18, S, cls18, rls18, idx18);
  }

  conv8_f<<<dim3(cdiv(1600, 64), 256), TPB, 0, stream>>>(W8, f18_0, f18_1, idx18, conv18b);
  pool_pair<<<dim3(cdiv(256 * 100, TPB), 2), TPB, 0, stream>>>(conv18b, t2_, f18p, t2p);

  // ---------------- conf14 -> idx14 (D=196, K2=1216; staged in conf12 region) ----
  {
    int L = 6400, S = 6400, K2 = 1216;
    int gx = cdiv(S, 256), gy = cdiv(L, 128);   // 25 x 50
    pack_split2<<<dim3(cdiv(L * K2, TPB), 2), TPB, 0, stream>>>(f14_0, f14_1, pA, pB, L, 196, K2, CA, CB);
    gemm_big<false><<<gx * gy, 512, 0, stream>>>(pA, pB, conf12, L, S, K2, gx, gy,
                                                 cps, nullptr);
    logsum_combine2<<<dim3(cdiv(S, TPB), 1), TPB, 0, stream>>>(cps, nullptr, S, gy, 0, pen14, nullptr);
    finalize_argmax<<<L, TPB, 0, stream>>>(conf12, S, pen14, idx14);
  }
  pool14<<<cdiv(392 * 100, TPB), TPB, 0, stream>>>(f14_0, f14_1, idx14, f14p);

  convt3_f<<<dim3(cdiv(100, 64), 128), TPB, 0, stream>>>(Wt3, t3, t2p, f18p, f14p, t3conv);
  pool_k<<<cdiv(128 * 25, TPB), TPB, 0, stream>>>(t3conv, t3d, 128, 10, 2);

  convt4_f<<<dim3(1, 128), TPB, 0, stream>>>(Wt4, t3d, t4, t4d);

  topic_k4<<<200, TPB, 0, stream>>>(f12_0, f12_1, t4d, topic);

  // ---------------- conf12 (output, D=128, K2=768) ----------------
  {
    int L = 6400, S = 6400, K2 = 768;
    int gx = cdiv(S, 256), gy = cdiv(L, 128);   // 25 x 50
    pack_split2<<<dim3(cdiv(L * K2, TPB), 2), TPB, 0, stream>>>(f12_0, f12_1, pA, pB, L, 128, K2, CA, CB);
    gemm_big<true><<<gx * gy, 512, 0, stream>>>(pA, pB, conf12, L, S, K2, gx, gy,
                                                cps, rps);
    logsum_combine2<<<dim3(cdiv(S, TPB), 2), TPB, 0, stream>>>(cps, rps, S, gy, gx, cls12, rls12);
    finalize_mask<<<L, TPB, 0, stream>>>(conf12, S, cls12, rls12);
  }
}

// Round 12
// 586.441 us; speedup vs baseline: 2.1999x; 2.1999x over previous
//
#include <hip/hip_runtime.h>
#include <math.h>

#define TPB 256
#define C0F 20.0f

typedef __attribute__((ext_vector_type(4))) float f32x4;
typedef short s16x8 __attribute__((ext_vector_type(8)));

static inline int cdiv(int a, int b) { return (a + b - 1) / b; }

#define GLOAD_LDS16(g, l)                                                        \
  __builtin_amdgcn_global_load_lds(                                              \
      (const __attribute__((address_space(1))) unsigned int*)(const void*)(g),   \
      (__attribute__((address_space(3))) unsigned int*)(void*)(l), 16, 0, 0)

__device__ __forceinline__ unsigned short f2bf_rne(float f) {
  unsigned int u = __float_as_uint(f);
  return (unsigned short)((u + 0x7FFFu + ((u >> 16) & 1u)) >> 16);
}
__device__ __forceinline__ float bf2f(unsigned short h) {
  return __uint_as_float(((unsigned int)h) << 16);
}

// ---------------- 3-term split-bf16 pack, A and B in one launch -------------
__global__ __launch_bounds__(TPB) void pack_split2(const float* __restrict__ XA,
                                                   const float* __restrict__ XB,
                                                   unsigned short* __restrict__ outA,
                                                   unsigned short* __restrict__ outB,
                                                   int M, int D, int K2p,
                                                   int codesA, int codesB) {
  int id = blockIdx.x * TPB + threadIdx.x;
  if (id >= M * K2p) return;
  const float* X = blockIdx.y ? XB : XA;
  unsigned short* out = blockIdx.y ? outB : outA;
  int codes = blockIdx.y ? codesB : codesA;
  int m = id / K2p, k = id - m * K2p;
  int s = k / D;
  unsigned short v = 0;
  if (s < 6) {
    int d = k - s * D;
    float a = X[(size_t)m * D + d];
    unsigned short h = f2bf_rne(a);
    int code = (codes >> (2 * s)) & 3;
    if (code == 0) {
      v = h;
    } else {
      float r1 = a - bf2f(h);
      unsigned short mi = f2bf_rne(r1);
      if (code == 1) v = mi;
      else v = f2bf_rne(r1 - bf2f(mi));
    }
  }
  out[id] = v;
}

// ---------------- small-GEMM (128x128, 4 waves) + fused exp-sum partials ----
template <bool EXACT, bool ROWSTATS>
__global__ __launch_bounds__(TPB) void gemm_bf16_nt(const unsigned short* __restrict__ A,
                                                    const unsigned short* __restrict__ B,
                                                    float* __restrict__ C,
                                                    int M, int N, int K, int gx, int gy,
                                                    float* __restrict__ cps,
                                                    float* __restrict__ rps) {
  __shared__ __align__(16) unsigned short As[128 * 64];
  __shared__ __align__(16) unsigned short Bs[128 * 64];
  const int tid = threadIdx.x;
  const int lane = tid & 63;
  const int w = tid >> 6;
  const int wm = w >> 1, wn = w & 1;

  const int nwg = gridDim.x;
  const int q = nwg >> 3, r = nwg & 7;
  const int xcd = blockIdx.x & 7, pos = blockIdx.x >> 3;
  const int wgid = (xcd < r ? xcd * (q + 1) : r * (q + 1) + (xcd - r) * q) + pos;
  const int tpg = 8 * gx;
  const int g = wgid / tpg;
  const int rem = wgid - g * tpg;
  const int rows = min(8, gy - g * 8);
  const int bx = rem / rows;
  const int by = g * 8 + rem - bx * rows;
  const int bm = by * 128, bn = bx * 128;

  f32x4 acc[4][4];
#pragma unroll
  for (int m = 0; m < 4; ++m)
#pragma unroll
    for (int n = 0; n < 4; ++n) acc[m][n] = (f32x4){0.f, 0.f, 0.f, 0.f};

  const unsigned short* gA[4];
  const unsigned short* gB[4];
#pragma unroll
  for (int i = 0; i < 4; ++i) {
    int qq = (w * 4 + i) * 64 + lane;
    int rr = qq >> 3;
    int cc = (qq & 7) ^ (rr & 7);
    int ga = bm + rr, gb = bn + rr;
    if (!EXACT) { if (ga >= M) ga = M - 1; if (gb >= N) gb = N - 1; }
    gA[i] = A + (size_t)ga * K + cc * 8;
    gB[i] = B + (size_t)gb * K + cc * 8;
  }

  for (int k0 = 0; k0 < K; k0 += 64) {
#pragma unroll
    for (int i = 0; i < 4; ++i) {
      GLOAD_LDS16(gA[i] + k0, As + (w * 4 + i) * 512);
      GLOAD_LDS16(gB[i] + k0, Bs + (w * 4 + i) * 512);
    }
    __syncthreads();
#pragma unroll
    for (int ks = 0; ks < 2; ++ks) {
      s16x8 af[4], bfr[4];
      const int c0 = ks * 4 + (lane >> 4);
#pragma unroll
      for (int m = 0; m < 4; ++m) {
        int ra = wm * 64 + m * 16 + (lane & 15);
        af[m] = *(const s16x8*)(As + ra * 64 + ((c0 ^ (ra & 7)) * 8));
        int rb = wn * 64 + m * 16 + (lane & 15);
        bfr[m] = *(const s16x8*)(Bs + rb * 64 + ((c0 ^ (rb & 7)) * 8));
      }
#pragma unroll
      for (int m = 0; m < 4; ++m)
#pragma unroll
        for (int n = 0; n < 4; ++n)
          acc[m][n] = __builtin_amdgcn_mfma_f32_16x16x32_bf16(af[m], bfr[n], acc[m][n], 0, 0, 0);
    }
    __syncthreads();
  }

#pragma unroll
  for (int m = 0; m < 4; ++m) {
    int row0 = bm + wm * 64 + m * 16 + (lane >> 4) * 4;
#pragma unroll
    for (int n = 0; n < 4; ++n) {
      int col = bn + wn * 64 + n * 16 + (lane & 15);
      if (EXACT || col < N) {
#pragma unroll
        for (int j = 0; j < 4; ++j) {
          int r2 = row0 + j;
          if (EXACT || r2 < M) C[(size_t)r2 * N + col] = acc[m][n][j];
        }
      }
    }
  }

#pragma unroll
  for (int m = 0; m < 4; ++m)
#pragma unroll
    for (int n = 0; n < 4; ++n)
#pragma unroll
      for (int j = 0; j < 4; ++j) acc[m][n][j] = __expf(acc[m][n][j] - C0F);

  float* scs = (float*)As;  // [8][128]
  const int slot = wm * 4 + (lane >> 4);
#pragma unroll
  for (int n = 0; n < 4; ++n) {
    int lcol = wn * 64 + n * 16 + (lane & 15);
    float s = 0.f;
#pragma unroll
    for (int m = 0; m < 4; ++m)
#pragma unroll
      for (int j = 0; j < 4; ++j) {
        if (!EXACT) {
          int grow = bm + wm * 64 + m * 16 + (lane >> 4) * 4 + j;
          if (grow >= M) continue;
        }
        s += acc[m][n][j];
      }
    scs[slot * 128 + lcol] = s;
  }
  __syncthreads();
  if (tid < 128) {
    float s = 0.f;
#pragma unroll
    for (int k = 0; k < 8; ++k) s += scs[k * 128 + tid];
    if (EXACT || bn + tid < N) cps[(size_t)by * N + bn + tid] = s;
  }

  if (ROWSTATS) {
    float* srs = (float*)Bs;  // [2][128]
#pragma unroll
    for (int m = 0; m < 4; ++m)
#pragma unroll
      for (int j = 0; j < 4; ++j) {
        float s = 0.f;
#pragma unroll
        for (int n = 0; n < 4; ++n) {
          if (!EXACT) {
            int gcol = bn + wn * 64 + n * 16 + (lane & 15);
            if (gcol >= N) continue;
          }
          s += acc[m][n][j];
        }
#pragma unroll
        for (int d = 1; d < 16; d <<= 1) s += __shfl_xor(s, d);
        if ((lane & 15) == 0) srs[wn * 128 + wm * 64 + m * 16 + (lane >> 4) * 4 + j] = s;
      }
    __syncthreads();
    if (tid < 128) {
      float s = srs[tid] + srs[128 + tid];
      if (EXACT || bm + tid < M) rps[(size_t)bx * M + bm + tid] = s;
    }
  }
}

// ---------------- big-GEMM (128x256, 8 waves, EXACT, BK=64 single-buffer) ----
// R7-proven (121 us, MfmaUtil 36%). R8: no min-occupancy (spills acc).
// R9: no BK=32 dbuf. R11: no gather-conv fusion (scatter x reuse-factor).
template <bool ROWSTATS>
__global__ __launch_bounds__(512) void gemm_big(const unsigned short* __restrict__ A,
                                                const unsigned short* __restrict__ B,
                                                float* __restrict__ C,
                                                int M, int N, int K, int gx, int gy,
                                                float* __restrict__ cps,
                                                float* __restrict__ rps) {
  __shared__ __align__(16) unsigned short As[128 * 64];   // 16 KB
  __shared__ __align__(16) unsigned short Bs[256 * 64];   // 32 KB
  const int tid = threadIdx.x;
  const int lane = tid & 63;
  const int w = tid >> 6;          // 0..7
  const int wm = w >> 2, wn = w & 3;

  const int nwg = gridDim.x;
  const int q = nwg >> 3, r = nwg & 7;
  const int xcd = blockIdx.x & 7, pos = blockIdx.x >> 3;
  const int wgid = (xcd < r ? xcd * (q + 1) : r * (q + 1) + (xcd - r) * q) + pos;
  const int tpg = 8 * gx;
  const int g = wgid / tpg;
  const int rem = wgid - g * tpg;
  const int rows = min(8, gy - g * 8);
  const int bx = rem / rows;
  const int by = g * 8 + rem - bx * rows;
  const int bm = by * 128, bn = bx * 256;

  f32x4 acc[4][4];
#pragma unroll
  for (int m = 0; m < 4; ++m)
#pragma unroll
    for (int n = 0; n < 4; ++n) acc[m][n] = (f32x4){0.f, 0.f, 0.f, 0.f};

  const unsigned short* gA[2];
  const unsigned short* gB[4];
#pragma unroll
  for (int i = 0; i < 2; ++i) {
    int qq = i * 512 + tid;
    int rr = qq >> 3;
    int cc = (qq & 7) ^ (rr & 7);
    gA[i] = A + (size_t)(bm + rr) * K + cc * 8;
  }
#pragma unroll
  for (int i = 0; i < 4; ++i) {
    int qq = i * 512 + tid;
    int rr = qq >> 3;
    int cc = (qq & 7) ^ (rr & 7);
    gB[i] = B + (size_t)(bn + rr) * K + cc * 8;
  }

  for (int k0 = 0; k0 < K; k0 += 64) {
#pragma unroll
    for (int i = 0; i < 2; ++i)
      GLOAD_LDS16(gA[i] + k0, As + (i * 8 + w) * 512);
#pragma unroll
    for (int i = 0; i < 4; ++i)
      GLOAD_LDS16(gB[i] + k0, Bs + (i * 8 + w) * 512);
    __syncthreads();
#pragma unroll
    for (int ks = 0; ks < 2; ++ks) {
      s16x8 af[4], bfr[4];
      const int c0 = ks * 4 + (lane >> 4);
#pragma unroll
      for (int m = 0; m < 4; ++m) {
        int ra = wm * 64 + m * 16 + (lane & 15);
        af[m] = *(const s16x8*)(As + ra * 64 + ((c0 ^ (ra & 7)) * 8));
        int rb = wn * 64 + m * 16 + (lane & 15);
        bfr[m] = *(const s16x8*)(Bs + rb * 64 + ((c0 ^ (rb & 7)) * 8));
      }
#pragma unroll
      for (int m = 0; m < 4; ++m)
#pragma unroll
        for (int n = 0; n < 4; ++n)
          acc[m][n] = __builtin_amdgcn_mfma_f32_16x16x32_bf16(af[m], bfr[n], acc[m][n], 0, 0, 0);
    }
    __syncthreads();
  }

#pragma unroll
  for (int m = 0; m < 4; ++m) {
    int row0 = bm + wm * 64 + m * 16 + (lane >> 4) * 4;
#pragma unroll
    for (int n = 0; n < 4; ++n) {
      int col = bn + wn * 64 + n * 16 + (lane & 15);
#pragma unroll
      for (int j = 0; j < 4; ++j)
        C[(size_t)(row0 + j) * N + col] = acc[m][n][j];
    }
  }

#pragma unroll
  for (int m = 0; m < 4; ++m)
#pragma unroll
    for (int n = 0; n < 4; ++n)
#pragma unroll
      for (int j = 0; j < 4; ++j) acc[m][n][j] = __expf(acc[m][n][j] - C0F);

  float* scs = (float*)As;  // [8][256]
  const int slot = wm * 4 + (lane >> 4);
#pragma unroll
  for (int n = 0; n < 4; ++n) {
    int lcol = wn * 64 + n * 16 + (lane & 15);
    float s = 0.f;
#pragma unroll
    for (int m = 0; m < 4; ++m)
#pragma unroll
      for (int j = 0; j < 4; ++j) s += acc[m][n][j];
    scs[slot * 256 + lcol] = s;
  }
  __syncthreads();
  if (tid < 256) {
    float s = 0.f;
#pragma unroll
    for (int k = 0; k < 8; ++k) s += scs[k * 256 + tid];
    cps[(size_t)by * N + bn + tid] = s;
  }

  if (ROWSTATS) {
    float* srs = (float*)Bs;  // [4][128]
#pragma unroll
    for (int m = 0; m < 4; ++m)
#pragma unroll
      for (int j = 0; j < 4; ++j) {
        float s = 0.f;
#pragma unroll
        for (int n = 0; n < 4; ++n) s += acc[m][n][j];
#pragma unroll
        for (int d = 1; d < 16; d <<= 1) s += __shfl_xor(s, d);
        if ((lane & 15) == 0) srs[wn * 128 + wm * 64 + m * 16 + (lane >> 4) * 4 + j] = s;
      }
    __syncthreads();
    if (tid < 128) {
      float s = (srs[tid] + srs[128 + tid]) + (srs[256 + tid] + srs[384 + tid]);
      rps[(size_t)bx * M + bm + tid] = s;
    }
  }
}

// ---------------- combine: out[s] = ln(sum of chunk partials) ----------------
__global__ __launch_bounds__(TPB) void logsum_combine2(const float* __restrict__ cps,
                                                       const float* __restrict__ rps,
                                                       int S, int nch_c, int nch_r,
                                                       float* __restrict__ out_c,
                                                       float* __restrict__ out_r) {
  int s = blockIdx.x * TPB + threadIdx.x;
  if (s >= S) return;
  const float* ps = blockIdx.y ? rps : cps;
  int nch = blockIdx.y ? nch_r : nch_c;
  float a = 0.f;
  for (int c = 0; c < nch; ++c) a += ps[(size_t)c * S + s];
  (blockIdx.y ? out_r : out_c)[s] = logf(a);
}

// ---------------- finalize variants ----------------
__global__ __launch_bounds__(TPB) void finalize_argmax(const float* __restrict__ sim, int S,
                                                       const float* __restrict__ pen,
                                                       int* __restrict__ amax) {
  __shared__ float rv[TPB];
  __shared__ int ri[TPB];
  const int l = blockIdx.x;
  const f32x4* row = (const f32x4*)(sim + (size_t)l * S);
  const f32x4* pv = (const f32x4*)pen;
  float bv = -INFINITY;
  int bi = 0;
  for (int j4 = threadIdx.x; j4 < (S >> 2); j4 += TPB) {
    f32x4 v = row[j4];
    f32x4 p = pv[j4];
#pragma unroll
    for (int k = 0; k < 4; ++k) {
      float sc = 2.f * v[k] - p[k];
      if (sc > bv) { bv = sc; bi = j4 * 4 + k; }
    }
  }
  rv[threadIdx.x] = bv;
  ri[threadIdx.x] = bi;
  __syncthreads();
  for (int stp = TPB / 2; stp > 0; stp >>= 1) {
    if (threadIdx.x < stp) {
      float v2 = rv[threadIdx.x + stp];
      int i2 = ri[threadIdx.x + stp];
      if (v2 > rv[threadIdx.x] || (v2 == rv[threadIdx.x] && i2 < ri[threadIdx.x])) {
        rv[threadIdx.x] = v2;
        ri[threadIdx.x] = i2;
      }
    }
    __syncthreads();
  }
  if (threadIdx.x == 0) amax[l] = ri[0];
}

__global__ __launch_bounds__(TPB) void finalize_write(float* __restrict__ sim, int S,
                                                      const float* __restrict__ cls,
                                                      const float* __restrict__ rls,
                                                      int* __restrict__ amax) {
  __shared__ float rv[TPB];
  __shared__ int ri[TPB];
  const int l = blockIdx.x;
  const float rl = rls[l] + 2.0f * C0F;
  f32x4* row = (f32x4*)(sim + (size_t)l * S);
  const f32x4* cv = (const f32x4*)cls;
  float bv = -INFINITY;
  int bi = 0;
  for (int j4 = threadIdx.x; j4 < (S >> 2); j4 += TPB) {
    f32x4 v = row[j4];
    f32x4 cl = cv[j4];
    f32x4 o;
#pragma unroll
    for (int k = 0; k < 4; ++k) {
      float conf = expf(2.f * v[k] - cl[k] - rl);
      o[k] = conf;
      if (conf > bv) { bv = conf; bi = j4 * 4 + k; }
    }
    row[j4] = o;
  }
  rv[threadIdx.x] = bv;
  ri[threadIdx.x] = bi;
  __syncthreads();
  for (int stp = TPB / 2; stp > 0; stp >>= 1) {
    if (threadIdx.x < stp) {
      float v2 = rv[threadIdx.x + stp];
      int i2 = ri[threadIdx.x + stp];
      if (v2 > rv[threadIdx.x] || (v2 == rv[threadIdx.x] && i2 < ri[threadIdx.x])) {
        rv[threadIdx.x] = v2;
        ri[threadIdx.x] = i2;
      }
    }
    __syncthreads();
  }
  if (threadIdx.x == 0) amax[l] = ri[0];
}

__global__ __launch_bounds__(TPB) void finalize_mask(float* __restrict__ sim, int S,
                                                     const float* __restrict__ cls,
                                                     const float* __restrict__ rls) {
  const int l = blockIdx.x;
  const float rl = rls[l] + 2.0f * C0F - 2.302585093f;  // -ln(10)
  f32x4* row = (f32x4*)(sim + (size_t)l * S);
  const f32x4* cv = (const f32x4*)cls;
  for (int j4 = threadIdx.x; j4 < (S >> 2); j4 += TPB) {
    f32x4 v = row[j4];
    f32x4 cl = cv[j4];
    f32x4 o;
#pragma unroll
    for (int k = 0; k < 4; ++k) {
      float c = expf(2.f * v[k] - cl[k] - rl);
      o[k] = (c > 1.0f) ? c : 0.0f;
    }
    row[j4] = o;
  }
}

// ---------------- small builders (R10-proven: gather once, conv coalesced) ----
__global__ void build_x16(const float* __restrict__ t2, const float* __restrict__ f0,
                          const float* __restrict__ f1, const int* __restrict__ idx,
                          float* __restrict__ X) {
  int id = blockIdx.x * TPB + threadIdx.x;
  if (id >= 768 * 400) return;
  int c = id / 400, p = id % 400;
  float v;
  if (c < 256) v = t2[p * 256 + c];
  else if (c < 512) v = f0[p * 256 + (c - 256)];
  else v = f1[idx[p] * 256 + (c - 512)];
  X[id] = v;
}

__global__ void build_x8(const float* __restrict__ f0, const float* __restrict__ f1,
                         const int* __restrict__ idx, float* __restrict__ X) {
  int id = blockIdx.x * TPB + threadIdx.x;
  if (id >= 512 * 1600) return;
  int c = id / 1600, p = id % 1600;
  float v = (c < 256) ? f0[p * 256 + c] : f1[idx[p] * 256 + (c - 256)];
  X[id] = v;
}

__global__ __launch_bounds__(TPB) void conv1x1_v2(const float* __restrict__ W,
                                                  const float* __restrict__ X,
                                                  float* __restrict__ Y,
                                                  int O, int C, int P) {
  __shared__ float red[TPB];
  const int o = blockIdx.y;
  const int pl = threadIdx.x & 63;
  const int p = blockIdx.x * 64 + pl;
  const int cg = threadIdx.x >> 6;
  const float* wr = W + (size_t)o * C;
  float a0 = 0.f, a1 = 0.f, a2 = 0.f, a3 = 0.f;
  if (p < P) {
    int c = cg;
    for (; c + 12 < C; c += 16) {
      a0 += wr[c]      * X[(size_t)c * P + p];
      a1 += wr[c + 4]  * X[(size_t)(c + 4) * P + p];
      a2 += wr[c + 8]  * X[(size_t)(c + 8) * P + p];
      a3 += wr[c + 12] * X[(size_t)(c + 12) * P + p];
    }
    for (; c < C; c += 4) a0 += wr[c] * X[(size_t)c * P + p];
  }
  red[threadIdx.x] = (a0 + a1) + (a2 + a3);
  __syncthreads();
  if (threadIdx.x < 64) {
    float s = (red[threadIdx.x] + red[threadIdx.x + 64]) +
              (red[threadIdx.x + 128] + red[threadIdx.x + 192]);
    if (p < P) Y[(size_t)o * P + p] = s;
  }
}

__global__ void pool_k(const float* __restrict__ in, float* __restrict__ out, int C, int H, int f) {
  int h = H / f;
  int id = blockIdx.x * TPB + threadIdx.x;
  if (id >= C * h * h) return;
  int c = id / (h * h);
  int r = id % (h * h);
  int py = r / h, px = r % h;
  float s = 0.f;
  for (int i = 0; i < f; ++i)
    for (int j = 0; j < f; ++j)
      s += in[(size_t)c * H * H + (size_t)(py * f + i) * H + (px * f + j)];
  out[id] = s / (float)(f * f);
}

// pool pair: y==0: conv18b (256,40,f4) -> f18p ; y==1: t2_ (256,20,f2) -> t2p
__global__ void pool_pair(const float* __restrict__ in0, const float* __restrict__ in1,
                          float* __restrict__ out0, float* __restrict__ out1) {
  int id = blockIdx.x * TPB + threadIdx.x;
  if (id >= 256 * 100) return;
  int c = id / 100;
  int r = id % 100;
  int py = r / 10, px = r % 10;
  if (blockIdx.y == 0) {
    float s = 0.f;
    for (int i = 0; i < 4; ++i)
      for (int j = 0; j < 4; ++j)
        s += in0[(size_t)c * 1600 + (size_t)(py * 4 + i) * 40 + (px * 4 + j)];
    out0[id] = s * 0.0625f;
  } else {
    float s = 0.f;
    for (int i = 0; i < 2; ++i)
      for (int j = 0; j < 2; ++j)
        s += in1[(size_t)c * 400 + (size_t)(py * 2 + i) * 20 + (px * 2 + j)];
    out1[id] = s * 0.25f;
  }
}

__global__ void pool14(const float* __restrict__ f0, const float* __restrict__ f1,
                       const int* __restrict__ idx, float* __restrict__ out) {
  int id = blockIdx.x * TPB + threadIdx.x;
  if (id >= 392 * 100) return;
  int c = id / 100;
  int r = id % 100;
  int py = r / 10, px = r % 10;
  float s = 0.f;
  for (int i = 0; i < 8; ++i)
    for (int j = 0; j < 8; ++j) {
      int p = (py * 8 + i) * 80 + (px * 8 + j);
      float v = (c < 196) ? f0[p * 196 + c] : f1[idx[p] * 196 + (c - 196)];
      s += v;
    }
  out[id] = s * (1.0f / 64.0f);
}

__global__ void build_xt3(const float* __restrict__ t3, const float* __restrict__ t2p,
                          const float* __restrict__ f18p, const float* __restrict__ f14p,
                          float* __restrict__ X) {
  int id = blockIdx.x * TPB + threadIdx.x;
  if (id >= 1100 * 100) return;
  int c = id / 100, p = id % 100;
  float v;
  if (c < 196) v = t3[p * 196 + c];
  else if (c < 452) v = t2p[(c - 196) * 100 + p];
  else if (c < 708) v = f18p[(c - 452) * 100 + p];
  else v = f14p[(c - 708) * 100 + p];
  X[id] = v;
}

__global__ void build_xt4(const float* __restrict__ t3d, const float* __restrict__ t4,
                          float* __restrict__ X) {
  int id = blockIdx.x * TPB + threadIdx.x;
  if (id >= 256 * 25) return;
  int c = id / 25, p = id % 25;
  X[id] = (c < 128) ? t3d[c * 25 + p] : t4[p * 128 + (c - 128)];
}

// ---------------- topic: 4 d-groups per row, 200 blocks ----------------
__global__ __launch_bounds__(TPB) void topic_k4(const float* __restrict__ f0,
                                                const float* __restrict__ f1,
                                                const float* __restrict__ t4d,
                                                float* __restrict__ out) {
  __shared__ float s_t4[25 * 128];     // 12.8 KB
  __shared__ float red[4 * 64 * 25];   // 25.6 KB
  for (int i = threadIdx.x; i < 25 * 128; i += TPB) {
    int k = i >> 7, d = i & 127;
    s_t4[i] = t4d[d * 25 + k];   // t4seq[k][d]
  }
  __syncthreads();
  const int r = threadIdx.x & 63;
  const int gq = threadIdx.x >> 6;
  const int m = blockIdx.x * 64 + r;
  const f32x4* row = (const f32x4*)((m < 6400) ? (f0 + (size_t)m * 128)
                                               : (f1 + (size_t)(m - 6400) * 128));
  float acc[25];
#pragma unroll
  for (int k = 0; k < 25; ++k) acc[k] = 0.f;
  for (int d4 = 0; d4 < 8; ++d4) {
    f32x4 x = row[gq * 8 + d4];
#pragma unroll
    for (int k = 0; k < 25; ++k) {
      const float* t = s_t4 + k * 128 + (gq * 8 + d4) * 4;
      acc[k] += x[0] * t[0] + x[1] * t[1] + x[2] * t[2] + x[3] * t[3];
    }
  }
#pragma unroll
  for (int k = 0; k < 25; ++k) red[(gq * 64 + r) * 25 + k] = acc[k];
  __syncthreads();
  if (gq == 0) {
    int best = 0;
    float bv = -INFINITY;
#pragma unroll
    for (int k = 0; k < 25; ++k) {
      float s = (red[r * 25 + k] + red[(64 + r) * 25 + k]) +
                (red[(128 + r) * 25 + k] + red[(192 + r) * 25 + k]);
      if (s > bv) { bv = s; best = k; }
    }
    out[m] = (float)best;
  }
}

extern "C" void kernel_launch(void* const* d_in, const int* in_sizes, int n_in,
                              void* d_out, int out_size, void* d_ws, size_t ws_size,
                              hipStream_t stream) {
  const float* f12_0 = (const float*)d_in[0];
  const float* f12_1 = (const float*)d_in[1];
  const float* f14_0 = (const float*)d_in[2];
  const float* f14_1 = (const float*)d_in[3];
  const float* f18_0 = (const float*)d_in[4];
  const float* f18_1 = (const float*)d_in[5];
  const float* f116_0 = (const float*)d_in[6];
  const float* f116_1 = (const float*)d_in[7];
  const float* t2 = (const float*)d_in[9];
  const float* t3 = (const float*)d_in[10];
  const float* t4 = (const float*)d_in[11];
  const float* W16 = (const float*)d_in[12];
  const float* W8 = (const float*)d_in[13];
  const float* Wt3 = (const float*)d_in[14];
  const float* Wt4 = (const float*)d_in[15];

  float* out = (float*)d_out;
  float* conf18 = out;
  float* conf12 = out + 2560000;
  float* topic = out + 2560000 + 40960000;

  float* w = (float*)d_ws;
  auto alloc = [&](size_t n) { float* p = w; w += ((n + 63) & ~(size_t)63); return p; };

  unsigned short* pA = (unsigned short*)alloc(6400 * 1216 / 2);
  unsigned short* pB = (unsigned short*)alloc(6400 * 1216 / 2);
  float* sim116 = alloc(400 * 400);
  float* pen116 = alloc(400);
  int* idx116 = (int*)alloc(400);
  float* cls18 = alloc(1600); float* rls18 = alloc(1600);
  int* idx18 = (int*)alloc(1600);
  float* pen14 = alloc(6400);
  int* idx14 = (int*)alloc(6400);
  float* cls12 = alloc(6400); float* rls12 = alloc(6400);
  float* cps = alloc(50 * 6400);
  float* rps = alloc(50 * 6400);
  float* X16 = alloc(768 * 400);
  float* t2_ = alloc(256 * 400);
  float* X8 = alloc(512 * 1600);
  float* conv18b = alloc(256 * 1600);
  float* f18p = alloc(256 * 100);
  float* t2p = alloc(256 * 100);
  float* f14p = alloc(392 * 100);
  float* Xt3 = alloc(1100 * 100);
  float* t3conv = alloc(128 * 100);
  float* t3d = alloc(128 * 25);
  float* Xt4 = alloc(256 * 25);
  float* t4d = alloc(128 * 25);

  // 6-section codes: A: [h,h,m,h,l,m]  B: [h,m,h,l,h,m]  ->  hh+hm+mh+hl+lh+mm
  const int CA = 0 | (0 << 2) | (1 << 4) | (0 << 6) | (2 << 8) | (1 << 10);
  const int CB = 0 | (1 << 2) | (0 << 4) | (2 << 6) | (0 << 8) | (1 << 10);

  // ---------------- conf116 -> idx116 (D=256, K2=1536) ----------------
  {
    int L = 400, S = 400, K2 = 1536;
    int gx = cdiv(S, 128), gy = cdiv(L, 128);
    pack_split2<<<dim3(cdiv(L * K2, TPB), 2), TPB, 0, stream>>>(f116_0, f116_1, pA, pB, L, 256, K2, CA, CB);
    gemm_bf16_nt<false, false><<<gx * gy, TPB, 0, stream>>>(pA, pB, sim116, L, S, K2, gx, gy,
                                                            cps, nullptr);
    logsum_combine2<<<dim3(cdiv(S, TPB), 1), TPB, 0, stream>>>(cps, nullptr, S, gy, 0, pen116, nullptr);
    finalize_argmax<<<L, TPB, 0, stream>>>(sim116, S, pen116, idx116);
  }

  build_x16<<<cdiv(768 * 400, TPB), TPB, 0, stream>>>(t2, f116_0, f116_1, idx116, X16);
  conv1x1_v2<<<dim3(cdiv(400, 64), 256), TPB, 0, stream>>>(W16, X16, t2_, 256, 768, 400);

  // ---------------- conf18 (output) + idx18 (D=256, K2=1536) ----------------
  {
    int L = 1600, S = 1600, K2 = 1536;
    int gx = cdiv(S, 128), gy = cdiv(L, 128);
    pack_split2<<<dim3(cdiv(L * K2, TPB), 2), TPB, 0, stream>>>(f18_0, f18_1, pA, pB, L, 256, K2, CA, CB);
    gemm_bf16_nt<false, true><<<gx * gy, TPB, 0, stream>>>(pA, pB, conf18, L, S, K2, gx, gy,
                                                           cps, rps);
    logsum_combine2<<<dim3(cdiv(S, TPB), 2), TPB, 0, stream>>>(cps, rps, S, gy, gx, cls18, rls18);
    finalize_write<<<L, TPB, 0, stream>>>(conf18, S, cls18, rls18, idx18);
  }

  build_x8<<<cdiv(512 * 1600, TPB), TPB, 0, stream>>>(f18_0, f18_1, idx18, X8);
  conv1x1_v2<<<dim3(cdiv(1600, 64), 256), TPB, 0, stream>>>(W8, X8, conv18b, 256, 512, 1600);
  pool_pair<<<dim3(cdiv(256 * 100, TPB), 2), TPB, 0, stream>>>(conv18b, t2_, f18p, t2p);

  // ---------------- conf14 -> idx14 (D=196, K2=1216; staged in conf12 region) ----
  {
    int L = 6400, S = 6400, K2 = 1216;
    int gx = cdiv(S, 256), gy = cdiv(L, 128);   // 25 x 50
    pack_split2<<<dim3(cdiv(L * K2, TPB), 2), TPB, 0, stream>>>(f14_0, f14_1, pA, pB, L, 196, K2, CA, CB);
    gemm_big<false><<<gx * gy, 512, 0, stream>>>(pA, pB, conf12, L, S, K2, gx, gy,
                                                 cps, nullptr);
    logsum_combine2<<<dim3(cdiv(S, TPB), 1), TPB, 0, stream>>>(cps, nullptr, S, gy, 0, pen14, nullptr);
    finalize_argmax<<<L, TPB, 0, stream>>>(conf12, S, pen14, idx14);
  }
  pool14<<<cdiv(392 * 100, TPB), TPB, 0, stream>>>(f14_0, f14_1, idx14, f14p);

  build_xt3<<<cdiv(1100 * 100, TPB), TPB, 0, stream>>>(t3, t2p, f18p, f14p, Xt3);
  conv1x1_v2<<<dim3(cdiv(100, 64), 128), TPB, 0, stream>>>(Wt3, Xt3, t3conv, 128, 1100, 100);
  pool_k<<<cdiv(128 * 25, TPB), TPB, 0, stream>>>(t3conv, t3d, 128, 10, 2);

  build_xt4<<<cdiv(256 * 25, TPB), TPB, 0, stream>>>(t3d, t4, Xt4);
  conv1x1_v2<<<dim3(cdiv(25, 64), 128), TPB, 0, stream>>>(Wt4, Xt4, t4d, 128, 256, 25);

  topic_k4<<<200, TPB, 0, stream>>>(f12_0, f12_1, t4d, topic);

  // ---------------- conf12 (output, D=128, K2=768) ----------------
  {
    int L = 6400, S = 6400, K2 = 768;
    int gx = cdiv(S, 256), gy = cdiv(L, 128);   // 25 x 50
    pack_split2<<<dim3(cdiv(L * K2, TPB), 2), TPB, 0, stream>>>(f12_0, f12_1, pA, pB, L, 128, K2, CA, CB);
    gemm_big<true><<<gx * gy, 512, 0, stream>>>(pA, pB, conf12, L, S, K2, gx, gy,
                                                cps, rps);
    logsum_combine2<<<dim3(cdiv(S, TPB), 2), TPB, 0, stream>>>(cps, rps, S, gy, gx, cls12, rls12);
    finalize_mask<<<L, TPB, 0, stream>>>(conf12, S, cls12, rls12);
  }
}

// Round 13
// 543.068 us; speedup vs baseline: 2.3756x; 1.0799x over previous
//
#include <hip/hip_runtime.h>
#include <math.h>

#define TPB 256
#define C0F 20.0f

typedef __attribute__((ext_vector_type(4))) float f32x4;
typedef short s16x8 __attribute__((ext_vector_type(8)));

static inline int cdiv(int a, int b) { return (a + b - 1) / b; }

#define GLOAD_LDS16(g, l)                                                        \
  __builtin_amdgcn_global_load_lds(                                              \
      (const __attribute__((address_space(1))) unsigned int*)(const void*)(g),   \
      (__attribute__((address_space(3))) unsigned int*)(void*)(l), 16, 0, 0)

__device__ __forceinline__ unsigned short f2bf_rne(float f) {
  unsigned int u = __float_as_uint(f);
  return (unsigned short)((u + 0x7FFFu + ((u >> 16) & 1u)) >> 16);
}
__device__ __forceinline__ float bf2f(unsigned short h) {
  return __uint_as_float(((unsigned int)h) << 16);
}

// ---------------- 3-term split pack v3: one thread per (m,d), 6 writes ------
// Computes h/mid/lo once, writes each of the 6 K-sections per its 2-bit code.
// Also zeroes the K2p pad region (pad = K2p - 6D < D assumed).
__global__ __launch_bounds__(TPB) void pack_split3(const float* __restrict__ XA,
                                                   const float* __restrict__ XB,
                                                   unsigned short* __restrict__ outA,
                                                   unsigned short* __restrict__ outB,
                                                   int M, int D, int K2p,
                                                   int codesA, int codesB) {
  int id = blockIdx.x * TPB + threadIdx.x;
  if (id >= M * D) return;
  const float* X = blockIdx.y ? XB : XA;
  unsigned short* out = blockIdx.y ? outB : outA;
  const int codes = blockIdx.y ? codesB : codesA;
  int m = id / D, d = id - m * D;
  float a = X[id];
  unsigned short h = f2bf_rne(a);
  float r1 = a - bf2f(h);
  unsigned short mi = f2bf_rne(r1);
  unsigned short lo = f2bf_rne(r1 - bf2f(mi));
  size_t base = (size_t)m * K2p + d;
#pragma unroll
  for (int s = 0; s < 6; ++s) {
    int code = (codes >> (2 * s)) & 3;
    unsigned short v = (code == 0) ? h : ((code == 1) ? mi : lo);
    out[base + s * D] = v;
  }
  int pad = K2p - 6 * D;
  if (d < pad) out[(size_t)m * K2p + 6 * D + d] = 0;
}

// ---------------- small-GEMM (128x128, 4 waves) + fused exp-sum partials ----
template <bool EXACT, bool ROWSTATS>
__global__ __launch_bounds__(TPB) void gemm_bf16_nt(const unsigned short* __restrict__ A,
                                                    const unsigned short* __restrict__ B,
                                                    float* __restrict__ C,
                                                    int M, int N, int K, int gx, int gy,
                                                    float* __restrict__ cps,
                                                    float* __restrict__ rps) {
  __shared__ __align__(16) unsigned short As[128 * 64];
  __shared__ __align__(16) unsigned short Bs[128 * 64];
  const int tid = threadIdx.x;
  const int lane = tid & 63;
  const int w = tid >> 6;
  const int wm = w >> 1, wn = w & 1;

  const int nwg = gridDim.x;
  const int q = nwg >> 3, r = nwg & 7;
  const int xcd = blockIdx.x & 7, pos = blockIdx.x >> 3;
  const int wgid = (xcd < r ? xcd * (q + 1) : r * (q + 1) + (xcd - r) * q) + pos;
  const int tpg = 8 * gx;
  const int g = wgid / tpg;
  const int rem = wgid - g * tpg;
  const int rows = min(8, gy - g * 8);
  const int bx = rem / rows;
  const int by = g * 8 + rem - bx * rows;
  const int bm = by * 128, bn = bx * 128;

  f32x4 acc[4][4];
#pragma unroll
  for (int m = 0; m < 4; ++m)
#pragma unroll
    for (int n = 0; n < 4; ++n) acc[m][n] = (f32x4){0.f, 0.f, 0.f, 0.f};

  const unsigned short* gA[4];
  const unsigned short* gB[4];
#pragma unroll
  for (int i = 0; i < 4; ++i) {
    int qq = (w * 4 + i) * 64 + lane;
    int rr = qq >> 3;
    int cc = (qq & 7) ^ (rr & 7);
    int ga = bm + rr, gb = bn + rr;
    if (!EXACT) { if (ga >= M) ga = M - 1; if (gb >= N) gb = N - 1; }
    gA[i] = A + (size_t)ga * K + cc * 8;
    gB[i] = B + (size_t)gb * K + cc * 8;
  }

  for (int k0 = 0; k0 < K; k0 += 64) {
#pragma unroll
    for (int i = 0; i < 4; ++i) {
      GLOAD_LDS16(gA[i] + k0, As + (w * 4 + i) * 512);
      GLOAD_LDS16(gB[i] + k0, Bs + (w * 4 + i) * 512);
    }
    __syncthreads();
#pragma unroll
    for (int ks = 0; ks < 2; ++ks) {
      s16x8 af[4], bfr[4];
      const int c0 = ks * 4 + (lane >> 4);
#pragma unroll
      for (int m = 0; m < 4; ++m) {
        int ra = wm * 64 + m * 16 + (lane & 15);
        af[m] = *(const s16x8*)(As + ra * 64 + ((c0 ^ (ra & 7)) * 8));
        int rb = wn * 64 + m * 16 + (lane & 15);
        bfr[m] = *(const s16x8*)(Bs + rb * 64 + ((c0 ^ (rb & 7)) * 8));
      }
#pragma unroll
      for (int m = 0; m < 4; ++m)
#pragma unroll
        for (int n = 0; n < 4; ++n)
          acc[m][n] = __builtin_amdgcn_mfma_f32_16x16x32_bf16(af[m], bfr[n], acc[m][n], 0, 0, 0);
    }
    __syncthreads();
  }

#pragma unroll
  for (int m = 0; m < 4; ++m) {
    int row0 = bm + wm * 64 + m * 16 + (lane >> 4) * 4;
#pragma unroll
    for (int n = 0; n < 4; ++n) {
      int col = bn + wn * 64 + n * 16 + (lane & 15);
      if (EXACT || col < N) {
#pragma unroll
        for (int j = 0; j < 4; ++j) {
          int r2 = row0 + j;
          if (EXACT || r2 < M) C[(size_t)r2 * N + col] = acc[m][n][j];
        }
      }
    }
  }

#pragma unroll
  for (int m = 0; m < 4; ++m)
#pragma unroll
    for (int n = 0; n < 4; ++n)
#pragma unroll
      for (int j = 0; j < 4; ++j) acc[m][n][j] = __expf(acc[m][n][j] - C0F);

  float* scs = (float*)As;  // [8][128]
  const int slot = wm * 4 + (lane >> 4);
#pragma unroll
  for (int n = 0; n < 4; ++n) {
    int lcol = wn * 64 + n * 16 + (lane & 15);
    float s = 0.f;
#pragma unroll
    for (int m = 0; m < 4; ++m)
#pragma unroll
      for (int j = 0; j < 4; ++j) {
        if (!EXACT) {
          int grow = bm + wm * 64 + m * 16 + (lane >> 4) * 4 + j;
          if (grow >= M) continue;
        }
        s += acc[m][n][j];
      }
    scs[slot * 128 + lcol] = s;
  }
  __syncthreads();
  if (tid < 128) {
    float s = 0.f;
#pragma unroll
    for (int k = 0; k < 8; ++k) s += scs[k * 128 + tid];
    if (EXACT || bn + tid < N) cps[(size_t)by * N + bn + tid] = s;
  }

  if (ROWSTATS) {
    float* srs = (float*)Bs;  // [2][128]
#pragma unroll
    for (int m = 0; m < 4; ++m)
#pragma unroll
      for (int j = 0; j < 4; ++j) {
        float s = 0.f;
#pragma unroll
        for (int n = 0; n < 4; ++n) {
          if (!EXACT) {
            int gcol = bn + wn * 64 + n * 16 + (lane & 15);
            if (gcol >= N) continue;
          }
          s += acc[m][n][j];
        }
#pragma unroll
        for (int d = 1; d < 16; d <<= 1) s += __shfl_xor(s, d);
        if ((lane & 15) == 0) srs[wn * 128 + wm * 64 + m * 16 + (lane >> 4) * 4 + j] = s;
      }
    __syncthreads();
    if (tid < 128) {
      float s = srs[tid] + srs[128 + tid];
      if (EXACT || bm + tid < M) rps[(size_t)bx * M + bm + tid] = s;
    }
  }
}

// ---------------- big-GEMM (128x256, 8 waves, EXACT, BK=64 single-buffer) ----
// R7-proven (121 us, MfmaUtil 36%). R8: no min-occupancy (spills acc).
// R9: no BK=32 dbuf. R11: no gather-conv fusion (scatter x reuse-factor).
template <bool ROWSTATS>
__global__ __launch_bounds__(512) void gemm_big(const unsigned short* __restrict__ A,
                                                const unsigned short* __restrict__ B,
                                                float* __restrict__ C,
                                                int M, int N, int K, int gx, int gy,
                                                float* __restrict__ cps,
                                                float* __restrict__ rps) {
  __shared__ __align__(16) unsigned short As[128 * 64];   // 16 KB
  __shared__ __align__(16) unsigned short Bs[256 * 64];   // 32 KB
  const int tid = threadIdx.x;
  const int lane = tid & 63;
  const int w = tid >> 6;          // 0..7
  const int wm = w >> 2, wn = w & 3;

  const int nwg = gridDim.x;
  const int q = nwg >> 3, r = nwg & 7;
  const int xcd = blockIdx.x & 7, pos = blockIdx.x >> 3;
  const int wgid = (xcd < r ? xcd * (q + 1) : r * (q + 1) + (xcd - r) * q) + pos;
  const int tpg = 8 * gx;
  const int g = wgid / tpg;
  const int rem = wgid - g * tpg;
  const int rows = min(8, gy - g * 8);
  const int bx = rem / rows;
  const int by = g * 8 + rem - bx * rows;
  const int bm = by * 128, bn = bx * 256;

  f32x4 acc[4][4];
#pragma unroll
  for (int m = 0; m < 4; ++m)
#pragma unroll
    for (int n = 0; n < 4; ++n) acc[m][n] = (f32x4){0.f, 0.f, 0.f, 0.f};

  const unsigned short* gA[2];
  const unsigned short* gB[4];
#pragma unroll
  for (int i = 0; i < 2; ++i) {
    int qq = i * 512 + tid;
    int rr = qq >> 3;
    int cc = (qq & 7) ^ (rr & 7);
    gA[i] = A + (size_t)(bm + rr) * K + cc * 8;
  }
#pragma unroll
  for (int i = 0; i < 4; ++i) {
    int qq = i * 512 + tid;
    int rr = qq >> 3;
    int cc = (qq & 7) ^ (rr & 7);
    gB[i] = B + (size_t)(bn + rr) * K + cc * 8;
  }

  for (int k0 = 0; k0 < K; k0 += 64) {
#pragma unroll
    for (int i = 0; i < 2; ++i)
      GLOAD_LDS16(gA[i] + k0, As + (i * 8 + w) * 512);
#pragma unroll
    for (int i = 0; i < 4; ++i)
      GLOAD_LDS16(gB[i] + k0, Bs + (i * 8 + w) * 512);
    __syncthreads();
#pragma unroll
    for (int ks = 0; ks < 2; ++ks) {
      s16x8 af[4], bfr[4];
      const int c0 = ks * 4 + (lane >> 4);
#pragma unroll
      for (int m = 0; m < 4; ++m) {
        int ra = wm * 64 + m * 16 + (lane & 15);
        af[m] = *(const s16x8*)(As + ra * 64 + ((c0 ^ (ra & 7)) * 8));
        int rb = wn * 64 + m * 16 + (lane & 15);
        bfr[m] = *(const s16x8*)(Bs + rb * 64 + ((c0 ^ (rb & 7)) * 8));
      }
#pragma unroll
      for (int m = 0; m < 4; ++m)
#pragma unroll
        for (int n = 0; n < 4; ++n)
          acc[m][n] = __builtin_amdgcn_mfma_f32_16x16x32_bf16(af[m], bfr[n], acc[m][n], 0, 0, 0);
    }
    __syncthreads();
  }

#pragma unroll
  for (int m = 0; m < 4; ++m) {
    int row0 = bm + wm * 64 + m * 16 + (lane >> 4) * 4;
#pragma unroll
    for (int n = 0; n < 4; ++n) {
      int col = bn + wn * 64 + n * 16 + (lane & 15);
#pragma unroll
      for (int j = 0; j < 4; ++j)
        C[(size_t)(row0 + j) * N + col] = acc[m][n][j];
    }
  }

#pragma unroll
  for (int m = 0; m < 4; ++m)
#pragma unroll
    for (int n = 0; n < 4; ++n)
#pragma unroll
      for (int j = 0; j < 4; ++j) acc[m][n][j] = __expf(acc[m][n][j] - C0F);

  float* scs = (float*)As;  // [8][256]
  const int slot = wm * 4 + (lane >> 4);
#pragma unroll
  for (int n = 0; n < 4; ++n) {
    int lcol = wn * 64 + n * 16 + (lane & 15);
    float s = 0.f;
#pragma unroll
    for (int m = 0; m < 4; ++m)
#pragma unroll
      for (int j = 0; j < 4; ++j) s += acc[m][n][j];
    scs[slot * 256 + lcol] = s;
  }
  __syncthreads();
  if (tid < 256) {
    float s = 0.f;
#pragma unroll
    for (int k = 0; k < 8; ++k) s += scs[k * 256 + tid];
    cps[(size_t)by * N + bn + tid] = s;
  }

  if (ROWSTATS) {
    float* srs = (float*)Bs;  // [4][128]
#pragma unroll
    for (int m = 0; m < 4; ++m)
#pragma unroll
      for (int j = 0; j < 4; ++j) {
        float s = 0.f;
#pragma unroll
        for (int n = 0; n < 4; ++n) s += acc[m][n][j];
#pragma unroll
        for (int d = 1; d < 16; d <<= 1) s += __shfl_xor(s, d);
        if ((lane & 15) == 0) srs[wn * 128 + wm * 64 + m * 16 + (lane >> 4) * 4 + j] = s;
      }
    __syncthreads();
    if (tid < 128) {
      float s = (srs[tid] + srs[128 + tid]) + (srs[256 + tid] + srs[384 + tid]);
      rps[(size_t)bx * M + bm + tid] = s;
    }
  }
}

// ---------------- combine: out[s] = ln(sum of chunk partials) ----------------
__global__ __launch_bounds__(TPB) void logsum_combine2(const float* __restrict__ cps,
                                                       const float* __restrict__ rps,
                                                       int S, int nch_c, int nch_r,
                                                       float* __restrict__ out_c,
                                                       float* __restrict__ out_r) {
  int s = blockIdx.x * TPB + threadIdx.x;
  if (s >= S) return;
  const float* ps = blockIdx.y ? rps : cps;
  int nch = blockIdx.y ? nch_r : nch_c;
  float a = 0.f;
  for (int c = 0; c < nch; ++c) a += ps[(size_t)c * S + s];
  (blockIdx.y ? out_r : out_c)[s] = logf(a);
}

// ---------------- finalize variants ----------------
__global__ __launch_bounds__(TPB) void finalize_argmax(const float* __restrict__ sim, int S,
                                                       const float* __restrict__ pen,
                                                       int* __restrict__ amax) {
  __shared__ float rv[TPB];
  __shared__ int ri[TPB];
  const int l = blockIdx.x;
  const f32x4* row = (const f32x4*)(sim + (size_t)l * S);
  const f32x4* pv = (const f32x4*)pen;
  float bv = -INFINITY;
  int bi = 0;
  for (int j4 = threadIdx.x; j4 < (S >> 2); j4 += TPB) {
    f32x4 v = row[j4];
    f32x4 p = pv[j4];
#pragma unroll
    for (int k = 0; k < 4; ++k) {
      float sc = 2.f * v[k] - p[k];
      if (sc > bv) { bv = sc; bi = j4 * 4 + k; }
    }
  }
  rv[threadIdx.x] = bv;
  ri[threadIdx.x] = bi;
  __syncthreads();
  for (int stp = TPB / 2; stp > 0; stp >>= 1) {
    if (threadIdx.x < stp) {
      float v2 = rv[threadIdx.x + stp];
      int i2 = ri[threadIdx.x + stp];
      if (v2 > rv[threadIdx.x] || (v2 == rv[threadIdx.x] && i2 < ri[threadIdx.x])) {
        rv[threadIdx.x] = v2;
        ri[threadIdx.x] = i2;
      }
    }
    __syncthreads();
  }
  if (threadIdx.x == 0) amax[l] = ri[0];
}

__global__ __launch_bounds__(TPB) void finalize_write(float* __restrict__ sim, int S,
                                                      const float* __restrict__ cls,
                                                      const float* __restrict__ rls,
                                                      int* __restrict__ amax) {
  __shared__ float rv[TPB];
  __shared__ int ri[TPB];
  const int l = blockIdx.x;
  const float rl = rls[l] + 2.0f * C0F;
  f32x4* row = (f32x4*)(sim + (size_t)l * S);
  const f32x4* cv = (const f32x4*)cls;
  float bv = -INFINITY;
  int bi = 0;
  for (int j4 = threadIdx.x; j4 < (S >> 2); j4 += TPB) {
    f32x4 v = row[j4];
    f32x4 cl = cv[j4];
    f32x4 o;
#pragma unroll
    for (int k = 0; k < 4; ++k) {
      float conf = expf(2.f * v[k] - cl[k] - rl);
      o[k] = conf;
      if (conf > bv) { bv = conf; bi = j4 * 4 + k; }
    }
    row[j4] = o;
  }
  rv[threadIdx.x] = bv;
  ri[threadIdx.x] = bi;
  __syncthreads();
  for (int stp = TPB / 2; stp > 0; stp >>= 1) {
    if (threadIdx.x < stp) {
      float v2 = rv[threadIdx.x + stp];
      int i2 = ri[threadIdx.x + stp];
      if (v2 > rv[threadIdx.x] || (v2 == rv[threadIdx.x] && i2 < ri[threadIdx.x])) {
        rv[threadIdx.x] = v2;
        ri[threadIdx.x] = i2;
      }
    }
    __syncthreads();
  }
  if (threadIdx.x == 0) amax[l] = ri[0];
}

__global__ __launch_bounds__(TPB) void finalize_mask(float* __restrict__ sim, int S,
                                                     const float* __restrict__ cls,
                                                     const float* __restrict__ rls) {
  const int l = blockIdx.x;
  const float rl = rls[l] + 2.0f * C0F - 2.302585093f;  // -ln(10)
  f32x4* row = (f32x4*)(sim + (size_t)l * S);
  const f32x4* cv = (const f32x4*)cls;
  for (int j4 = threadIdx.x; j4 < (S >> 2); j4 += TPB) {
    f32x4 v = row[j4];
    f32x4 cl = cv[j4];
    f32x4 o;
#pragma unroll
    for (int k = 0; k < 4; ++k) {
      float c = expf(2.f * v[k] - cl[k] - rl);
      o[k] = (c > 1.0f) ? c : 0.0f;
    }
    row[j4] = o;
  }
}

// ---------------- small builders (gather once, conv coalesced) ----------------
__global__ void build_x16(const float* __restrict__ t2, const float* __restrict__ f0,
                          const float* __restrict__ f1, const int* __restrict__ idx,
                          float* __restrict__ X) {
  int id = blockIdx.x * TPB + threadIdx.x;
  if (id >= 768 * 400) return;
  int c = id / 400, p = id % 400;
  float v;
  if (c < 256) v = t2[p * 256 + c];
  else if (c < 512) v = f0[p * 256 + (c - 256)];
  else v = f1[idx[p] * 256 + (c - 512)];
  X[id] = v;
}

__global__ void build_x8(const float* __restrict__ f0, const float* __restrict__ f1,
                         const int* __restrict__ idx, float* __restrict__ X) {
  int id = blockIdx.x * TPB + threadIdx.x;
  if (id >= 512 * 1600) return;
  int c = id / 1600, p = id % 1600;
  float v = (c < 256) ? f0[p * 256 + c] : f1[idx[p] * 256 + (c - 256)];
  X[id] = v;
}

__global__ __launch_bounds__(TPB) void conv1x1_v2(const float* __restrict__ W,
                                                  const float* __restrict__ X,
                                                  float* __restrict__ Y,
                                                  int O, int C, int P) {
  __shared__ float red[TPB];
  const int o = blockIdx.y;
  const int pl = threadIdx.x & 63;
  const int p = blockIdx.x * 64 + pl;
  const int cg = threadIdx.x >> 6;
  const float* wr = W + (size_t)o * C;
  float a0 = 0.f, a1 = 0.f, a2 = 0.f, a3 = 0.f;
  if (p < P) {
    int c = cg;
    for (; c + 12 < C; c += 16) {
      a0 += wr[c]      * X[(size_t)c * P + p];
      a1 += wr[c + 4]  * X[(size_t)(c + 4) * P + p];
      a2 += wr[c + 8]  * X[(size_t)(c + 8) * P + p];
      a3 += wr[c + 12] * X[(size_t)(c + 12) * P + p];
    }
    for (; c < C; c += 4) a0 += wr[c] * X[(size_t)c * P + p];
  }
  red[threadIdx.x] = (a0 + a1) + (a2 + a3);
  __syncthreads();
  if (threadIdx.x < 64) {
    float s = (red[threadIdx.x] + red[threadIdx.x + 64]) +
              (red[threadIdx.x + 128] + red[threadIdx.x + 192]);
    if (p < P) Y[(size_t)o * P + p] = s;
  }
}

__global__ void pool_k(const float* __restrict__ in, float* __restrict__ out, int C, int H, int f) {
  int h = H / f;
  int id = blockIdx.x * TPB + threadIdx.x;
  if (id >= C * h * h) return;
  int c = id / (h * h);
  int r = id % (h * h);
  int py = r / h, px = r % h;
  float s = 0.f;
  for (int i = 0; i < f; ++i)
    for (int j = 0; j < f; ++j)
      s += in[(size_t)c * H * H + (size_t)(py * f + i) * H + (px * f + j)];
  out[id] = s / (float)(f * f);
}

// pool pair: y==0: conv18b (256,40,f4) -> f18p ; y==1: t2_ (256,20,f2) -> t2p
__global__ void pool_pair(const float* __restrict__ in0, const float* __restrict__ in1,
                          float* __restrict__ out0, float* __restrict__ out1) {
  int id = blockIdx.x * TPB + threadIdx.x;
  if (id >= 256 * 100) return;
  int c = id / 100;
  int r = id % 100;
  int py = r / 10, px = r % 10;
  if (blockIdx.y == 0) {
    float s = 0.f;
    for (int i = 0; i < 4; ++i)
      for (int j = 0; j < 4; ++j)
        s += in0[(size_t)c * 1600 + (size_t)(py * 4 + i) * 40 + (px * 4 + j)];
    out0[id] = s * 0.0625f;
  } else {
    float s = 0.f;
    for (int i = 0; i < 2; ++i)
      for (int j = 0; j < 2; ++j)
        s += in1[(size_t)c * 400 + (size_t)(py * 2 + i) * 20 + (px * 2 + j)];
    out1[id] = s * 0.25f;
  }
}

__global__ void pool14(const float* __restrict__ f0, const float* __restrict__ f1,
                       const int* __restrict__ idx, float* __restrict__ out) {
  int id = blockIdx.x * TPB + threadIdx.x;
  if (id >= 392 * 100) return;
  int c = id / 100;
  int r = id % 100;
  int py = r / 10, px = r % 10;
  float s = 0.f;
  for (int i = 0; i < 8; ++i)
    for (int j = 0; j < 8; ++j) {
      int p = (py * 8 + i) * 80 + (px * 8 + j);
      float v = (c < 196) ? f0[p * 196 + c] : f1[idx[p] * 196 + (c - 196)];
      s += v;
    }
  out[id] = s * (1.0f / 64.0f);
}

__global__ void build_xt3(const float* __restrict__ t3, const float* __restrict__ t2p,
                          const float* __restrict__ f18p, const float* __restrict__ f14p,
                          float* __restrict__ X) {
  int id = blockIdx.x * TPB + threadIdx.x;
  if (id >= 1100 * 100) return;
  int c = id / 100, p = id % 100;
  float v;
  if (c < 196) v = t3[p * 196 + c];
  else if (c < 452) v = t2p[(c - 196) * 100 + p];
  else if (c < 708) v = f18p[(c - 452) * 100 + p];
  else v = f14p[(c - 708) * 100 + p];
  X[id] = v;
}

__global__ void build_xt4(const float* __restrict__ t3d, const float* __restrict__ t4,
                          float* __restrict__ X) {
  int id = blockIdx.x * TPB + threadIdx.x;
  if (id >= 256 * 25) return;
  int c = id / 25, p = id % 25;
  X[id] = (c < 128) ? t3d[c * 25 + p] : t4[p * 128 + (c - 128)];
}

// ---------------- topic: 4 d-groups per row, 200 blocks ----------------
__global__ __launch_bounds__(TPB) void topic_k4(const float* __restrict__ f0,
                                                const float* __restrict__ f1,
                                                const float* __restrict__ t4d,
                                                float* __restrict__ out) {
  __shared__ float s_t4[25 * 128];     // 12.8 KB
  __shared__ float red[4 * 64 * 25];   // 25.6 KB
  for (int i = threadIdx.x; i < 25 * 128; i += TPB) {
    int k = i >> 7, d = i & 127;
    s_t4[i] = t4d[d * 25 + k];   // t4seq[k][d]
  }
  __syncthreads();
  const int r = threadIdx.x & 63;
  const int gq = threadIdx.x >> 6;
  const int m = blockIdx.x * 64 + r;
  const f32x4* row = (const f32x4*)((m < 6400) ? (f0 + (size_t)m * 128)
                                               : (f1 + (size_t)(m - 6400) * 128));
  float acc[25];
#pragma unroll
  for (int k = 0; k < 25; ++k) acc[k] = 0.f;
  for (int d4 = 0; d4 < 8; ++d4) {
    f32x4 x = row[gq * 8 + d4];
#pragma unroll
    for (int k = 0; k < 25; ++k) {
      const float* t = s_t4 + k * 128 + (gq * 8 + d4) * 4;
      acc[k] += x[0] * t[0] + x[1] * t[1] + x[2] * t[2] + x[3] * t[3];
    }
  }
#pragma unroll
  for (int k = 0; k < 25; ++k) red[(gq * 64 + r) * 25 + k] = acc[k];
  __syncthreads();
  if (gq == 0) {
    int best = 0;
    float bv = -INFINITY;
#pragma unroll
    for (int k = 0; k < 25; ++k) {
      float s = (red[r * 25 + k] + red[(64 + r) * 25 + k]) +
                (red[(128 + r) * 25 + k] + red[(192 + r) * 25 + k]);
      if (s > bv) { bv = s; best = k; }
    }
    out[m] = (float)best;
  }
}

extern "C" void kernel_launch(void* const* d_in, const int* in_sizes, int n_in,
                              void* d_out, int out_size, void* d_ws, size_t ws_size,
                              hipStream_t stream) {
  const float* f12_0 = (const float*)d_in[0];
  const float* f12_1 = (const float*)d_in[1];
  const float* f14_0 = (const float*)d_in[2];
  const float* f14_1 = (const float*)d_in[3];
  const float* f18_0 = (const float*)d_in[4];
  const float* f18_1 = (const float*)d_in[5];
  const float* f116_0 = (const float*)d_in[6];
  const float* f116_1 = (const float*)d_in[7];
  const float* t2 = (const float*)d_in[9];
  const float* t3 = (const float*)d_in[10];
  const float* t4 = (const float*)d_in[11];
  const float* W16 = (const float*)d_in[12];
  const float* W8 = (const float*)d_in[13];
  const float* Wt3 = (const float*)d_in[14];
  const float* Wt4 = (const float*)d_in[15];

  float* out = (float*)d_out;
  float* conf18 = out;
  float* conf12 = out + 2560000;
  float* topic = out + 2560000 + 40960000;

  float* w = (float*)d_ws;
  auto alloc = [&](size_t n) { float* p = w; w += ((n + 63) & ~(size_t)63); return p; };

  unsigned short* pA = (unsigned short*)alloc(6400 * 1216 / 2);
  unsigned short* pB = (unsigned short*)alloc(6400 * 1216 / 2);
  float* sim116 = alloc(400 * 400);
  float* pen116 = alloc(400);
  int* idx116 = (int*)alloc(400);
  float* cls18 = alloc(1600); float* rls18 = alloc(1600);
  int* idx18 = (int*)alloc(1600);
  float* pen14 = alloc(6400);
  int* idx14 = (int*)alloc(6400);
  float* cls12 = alloc(6400); float* rls12 = alloc(6400);
  float* cps = alloc(50 * 6400);
  float* rps = alloc(50 * 6400);
  float* X16 = alloc(768 * 400);
  float* t2_ = alloc(256 * 400);
  float* X8 = alloc(512 * 1600);
  float* conv18b = alloc(256 * 1600);
  float* f18p = alloc(256 * 100);
  float* t2p = alloc(256 * 100);
  float* f14p = alloc(392 * 100);
  float* Xt3 = alloc(1100 * 100);
  float* t3conv = alloc(128 * 100);
  float* t3d = alloc(128 * 25);
  float* Xt4 = alloc(256 * 25);
  float* t4d = alloc(128 * 25);

  // 6-section codes: A: [h,h,m,h,l,m]  B: [h,m,h,l,h,m]  ->  hh+hm+mh+hl+lh+mm
  const int CA = 0 | (0 << 2) | (1 << 4) | (0 << 6) | (2 << 8) | (1 << 10);
  const int CB = 0 | (1 << 2) | (0 << 4) | (2 << 6) | (0 << 8) | (1 << 10);

  // ---------------- conf116 -> idx116 (D=256, K2=1536) ----------------
  {
    int L = 400, S = 400, K2 = 1536;
    int gx = cdiv(S, 128), gy = cdiv(L, 128);
    pack_split3<<<dim3(cdiv(L * 256, TPB), 2), TPB, 0, stream>>>(f116_0, f116_1, pA, pB, L, 256, K2, CA, CB);
    gemm_bf16_nt<false, false><<<gx * gy, TPB, 0, stream>>>(pA, pB, sim116, L, S, K2, gx, gy,
                                                            cps, nullptr);
    logsum_combine2<<<dim3(cdiv(S, TPB), 1), TPB, 0, stream>>>(cps, nullptr, S, gy, 0, pen116, nullptr);
    finalize_argmax<<<L, TPB, 0, stream>>>(sim116, S, pen116, idx116);
  }

  build_x16<<<cdiv(768 * 400, TPB), TPB, 0, stream>>>(t2, f116_0, f116_1, idx116, X16);
  conv1x1_v2<<<dim3(cdiv(400, 64), 256), TPB, 0, stream>>>(W16, X16, t2_, 256, 768, 400);

  // ---------------- conf18 (output) + idx18 (D=256, K2=1536) ----------------
  {
    int L = 1600, S = 1600, K2 = 1536;
    int gx = cdiv(S, 128), gy = cdiv(L, 128);
    pack_split3<<<dim3(cdiv(L * 256, TPB), 2), TPB, 0, stream>>>(f18_0, f18_1, pA, pB, L, 256, K2, CA, CB);
    gemm_bf16_nt<false, true><<<gx * gy, TPB, 0, stream>>>(pA, pB, conf18, L, S, K2, gx, gy,
                                                           cps, rps);
    logsum_combine2<<<dim3(cdiv(S, TPB), 2), TPB, 0, stream>>>(cps, rps, S, gy, gx, cls18, rls18);
    finalize_write<<<L, TPB, 0, stream>>>(conf18, S, cls18, rls18, idx18);
  }

  build_x8<<<cdiv(512 * 1600, TPB), TPB, 0, stream>>>(f18_0, f18_1, idx18, X8);
  conv1x1_v2<<<dim3(cdiv(1600, 64), 256), TPB, 0, stream>>>(W8, X8, conv18b, 256, 512, 1600);
  pool_pair<<<dim3(cdiv(256 * 100, TPB), 2), TPB, 0, stream>>>(conv18b, t2_, f18p, t2p);

  // ---------------- conf14 -> idx14 (D=196, K2=1216; staged in conf12 region) ----
  {
    int L = 6400, S = 6400, K2 = 1216;
    int gx = cdiv(S, 256), gy = cdiv(L, 128);   // 25 x 50
    pack_split3<<<dim3(cdiv(L * 196, TPB), 2), TPB, 0, stream>>>(f14_0, f14_1, pA, pB, L, 196, K2, CA, CB);
    gemm_big<false><<<gx * gy, 512, 0, stream>>>(pA, pB, conf12, L, S, K2, gx, gy,
                                                 cps, nullptr);
    logsum_combine2<<<dim3(cdiv(S, TPB), 1), TPB, 0, stream>>>(cps, nullptr, S, gy, 0, pen14, nullptr);
    finalize_argmax<<<L, TPB, 0, stream>>>(conf12, S, pen14, idx14);
  }
  pool14<<<cdiv(392 * 100, TPB), TPB, 0, stream>>>(f14_0, f14_1, idx14, f14p);

  build_xt3<<<cdiv(1100 * 100, TPB), TPB, 0, stream>>>(t3, t2p, f18p, f14p, Xt3);
  conv1x1_v2<<<dim3(cdiv(100, 64), 128), TPB, 0, stream>>>(Wt3, Xt3, t3conv, 128, 1100, 100);
  pool_k<<<cdiv(128 * 25, TPB), TPB, 0, stream>>>(t3conv, t3d, 128, 10, 2);

  build_xt4<<<cdiv(256 * 25, TPB), TPB, 0, stream>>>(t3d, t4, Xt4);
  conv1x1_v2<<<dim3(cdiv(25, 64), 128), TPB, 0, stream>>>(Wt4, Xt4, t4d, 128, 256, 25);

  topic_k4<<<200, TPB, 0, stream>>>(f12_0, f12_1, t4d, topic);

  // ---------------- conf12 (output, D=128, K2=768) ----------------
  {
    int L = 6400, S = 6400, K2 = 768;
    int gx = cdiv(S, 256), gy = cdiv(L, 128);   // 25 x 50
    pack_split3<<<dim3(cdiv(L * 128, TPB), 2), TPB, 0, stream>>>(f12_0, f12_1, pA, pB, L, 128, K2, CA, CB);
    gemm_big<true><<<gx * gy, 512, 0, stream>>>(pA, pB, conf12, L, S, K2, gx, gy,
                                                cps, rps);
    logsum_combine2<<<dim3(cdiv(S, TPB), 2), TPB, 0, stream>>>(cps, rps, S, gy, gx, cls12, rls12);
    finalize_mask<<<L, TPB, 0, stream>>>(conf12, S, cls12, rls12);
  }
}